// Round 1
// baseline (602.012 us; speedup 1.0000x reference)
//
#include <hip/hip_runtime.h>

typedef __attribute__((ext_vector_type(4))) float f32x4;
typedef __attribute__((ext_vector_type(8))) short short8;
typedef __attribute__((ext_vector_type(4))) unsigned short us4;
typedef unsigned short u16;
typedef unsigned int u32;

#define B_   16
#define N_   2048
#define C_   256
#define CIN  131
#define COUT 128
#define L2E  1.44269504088896f

__device__ __forceinline__ u16 f2bf(float x) {
    u32 u = __float_as_uint(x);
    u32 r = (u + 0x7fffu + ((u >> 16) & 1u)) >> 16;
    return (u16)r;
}
__device__ __forceinline__ float bf2f(u16 h) {
    return __uint_as_float(((u32)h) << 16);
}

__device__ __forceinline__ f32x4 mfma16(short8 a, short8 b, f32x4 c) {
    return __builtin_amdgcn_mfma_f32_16x16x32_bf16(a, b, c, 0, 0, 0);
}

// ---------------------------------------------------------------------------
// Kernel 1: Wf -> fragment-major hi/lo bf16, plus folded BN scale/bias for bn_f
// wff[(og*8+cc)*64 + l][j] = Wf[o = og*16+(l&15)][c = cc*32+(l>>4)*8+j]
// ---------------------------------------------------------------------------
__global__ __launch_bounds__(256) void wf_prep(
    const float* __restrict__ Wf, const float* __restrict__ bnf,
    u16* __restrict__ wfh, u16* __restrict__ wfl,
    float* __restrict__ sf, float* __restrict__ tf)
{
    int t = threadIdx.x;
    for (int idx = t; idx < 8 * 8 * 64; idx += 256) {
        int og = idx >> 9;
        int cc = (idx >> 6) & 7;
        int l  = idx & 63;
        int o  = og * 16 + (l & 15);
        int c0 = cc * 32 + (l >> 4) * 8;
        #pragma unroll
        for (int j = 0; j < 8; ++j) {
            float f = Wf[o * 256 + c0 + j];
            u16 h = f2bf(f);
            wfh[(size_t)idx * 8 + j] = h;
            wfl[(size_t)idx * 8 + j] = f2bf(f - bf2f(h));
        }
    }
    if (t < COUT) {
        float g  = bnf[t];
        float be = bnf[128 + t];
        float mu = bnf[256 + t];
        float va = bnf[384 + t];
        float s = g * rsqrtf(va + 1e-5f);
        sf[t] = s;
        tf[t] = be - mu * s;
    }
}

// ---------------------------------------------------------------------------
// Kernel 2: QKV projection + BN + ReLU, fp32 vector math.
// Writes q/k/v as hi/lo bf16 in MFMA-fragment-major layouts:
//  qf[b][ng][cc][l][j]     : A-frag for S   (row n = ng*16+(l&15), k c = cc*32+(l>>4)*8+j)
//  kf[b][mc][mg][cc][l][j] : B-frag for S   (k c as above, col m = mc*32+mg*16+(l&15))
//  vf[b][mc][cg][l][j]     : B-frag for PV  (k m = mc*32+(l>>4)*8+j, col c = cg*16+(l&15))
// ---------------------------------------------------------------------------
__global__ __launch_bounds__(256, 2) void stage_qkv(
    const float* __restrict__ x,
    const float* __restrict__ Wq, const float* __restrict__ Wk, const float* __restrict__ Wv,
    const float* __restrict__ bnq, const float* __restrict__ bnk, const float* __restrict__ bnv,
    u16* __restrict__ qh, u16* __restrict__ ql,
    u16* __restrict__ kh, u16* __restrict__ kl,
    u16* __restrict__ vh, u16* __restrict__ vl)
{
    __shared__ __align__(16) float xs[CIN * 64];   // [i][n_local]
    __shared__ __align__(16) float wt[CIN * 64];   // [i][oc_local] (W^T chunk)

    int b  = blockIdx.x >> 5;
    int n0 = (blockIdx.x & 31) * 64;
    int t  = threadIdx.x;
    int tc = t & 15, tr = t >> 4;

    // load x tile [131][64]
    {
        int col = tc * 4;
        for (int r = tr; r < CIN; r += 16) {
            f32x4 vx = *(const f32x4*)(x + ((size_t)b * CIN + r) * N_ + n0 + col);
            *(f32x4*)&xs[r * 64 + col] = vx;
        }
    }

    for (int chunk = 0; chunk < 12; ++chunk) {
        int which = chunk >> 2;           // 0=q,1=k,2=v
        int cbase = (chunk & 3) * 64;     // channel base within matrix
        const float* W = (which == 0) ? Wq : (which == 1 ? Wk : Wv);

        __syncthreads();  // protect wt from previous iteration's readers
        for (int idx = t; idx < 64 * CIN; idx += 256) {
            int r = idx & 63;
            int i = idx >> 6;
            wt[i * 64 + r] = W[(size_t)(cbase + r) * CIN + i];
        }
        __syncthreads();

        float acc[4][4];
        #pragma unroll
        for (int ii = 0; ii < 4; ++ii)
            #pragma unroll
            for (int jj = 0; jj < 4; ++jj) acc[ii][jj] = 0.f;

        for (int i = 0; i < CIN; ++i) {
            f32x4 wv = *(const f32x4*)&wt[i * 64 + tc * 4];
            f32x4 xv = *(const f32x4*)&xs[i * 64 + tr * 4];
            #pragma unroll
            for (int ii = 0; ii < 4; ++ii)
                #pragma unroll
                for (int jj = 0; jj < 4; ++jj)
                    acc[ii][jj] = fmaf(wv[ii], xv[jj], acc[ii][jj]);
        }

        const float* bn = (which == 0) ? bnq : (which == 1 ? bnk : bnv);
        int c0 = cbase + tc * 4;          // channel base for this thread (0..255)
        int nb = n0 + tr * 4;             // n base for this thread
        u16 hh[4][4], hl[4][4];
        #pragma unroll
        for (int ii = 0; ii < 4; ++ii) {
            int c = c0 + ii;
            float g  = bn[c];
            float be = bn[256 + c];
            float mu = bn[512 + c];
            float va = bn[768 + c];
            float s  = g * rsqrtf(va + 1e-5f);
            float tb = be - mu * s;
            #pragma unroll
            for (int jj = 0; jj < 4; ++jj) {
                float z = fmaxf(fmaf(acc[ii][jj], s, tb), 0.f);
                u16 h = f2bf(z);
                hh[ii][jj] = h;
                hl[ii][jj] = f2bf(z - bf2f(h));
            }
        }

        if (which < 2) {
            u16* dh = which ? kh : qh;
            u16* dl = which ? kl : ql;
            #pragma unroll
            for (int jj = 0; jj < 4; ++jj) {
                int n = nb + jj;
                size_t base;
                if (which == 0) {
                    base = ((((size_t)b * 128 + (n >> 4)) * 8 + (c0 >> 5)) * 64
                            + ((c0 >> 3) & 3) * 16 + (n & 15)) * 8 + (c0 & 7);
                } else {
                    base = (((((size_t)b * 64 + (n >> 5)) * 2 + ((n >> 4) & 1)) * 8 + (c0 >> 5)) * 64
                            + ((c0 >> 3) & 3) * 16 + (n & 15)) * 8 + (c0 & 7);
                }
                us4 v0 = { hh[0][jj], hh[1][jj], hh[2][jj], hh[3][jj] };
                us4 v1 = { hl[0][jj], hl[1][jj], hl[2][jj], hl[3][jj] };
                *(us4*)(dh + base) = v0;
                *(us4*)(dl + base) = v1;
            }
        } else {
            #pragma unroll
            for (int ii = 0; ii < 4; ++ii) {
                int c = c0 + ii;
                size_t base = ((((size_t)b * 64 + (nb >> 5)) * 16 + (c >> 4)) * 64
                               + ((nb >> 3) & 3) * 16 + (c & 15)) * 8 + (nb & 7);
                us4 v0 = { hh[ii][0], hh[ii][1], hh[ii][2], hh[ii][3] };
                us4 v1 = { hl[ii][0], hl[ii][1], hl[ii][2], hl[ii][3] };
                *(us4*)(vh + base) = v0;
                *(us4*)(vl + base) = v1;
            }
        }
    }
}

// ---------------------------------------------------------------------------
// Kernel 3: flash attention (3-pass hi/lo bf16 MFMA = fp32-accurate) with fused
// final conv + BN + ReLU epilogue.
// Block: 256 threads = 4 waves; wave w owns 16 q-rows (ng = nt*4 + w).
// LDS (72KB): KT_HI[2][8][64][8] @0, KT_LO @8192, VT_HI[16][64][8] @16384,
//             VT_LO @24576, PH[4][64][8] @32768, PL @34816  (u16 units)
// ---------------------------------------------------------------------------
__global__ __launch_bounds__(256, 2) void attn_fwd(
    const u16* __restrict__ qh, const u16* __restrict__ ql,
    const u16* __restrict__ kh, const u16* __restrict__ kl,
    const u16* __restrict__ vh, const u16* __restrict__ vl,
    const u16* __restrict__ wfh, const u16* __restrict__ wfl,
    const float* __restrict__ sf, const float* __restrict__ tf,
    float* __restrict__ out)
{
    __shared__ __align__(16) u16 smem[36864];

    int bid = blockIdx.x;
    int swz = (bid & 7) * 64 + (bid >> 3);   // XCD-chunked swizzle (bijective, 512 blocks)
    int b   = swz >> 5;
    int nt  = swz & 31;
    int tid = threadIdx.x;
    int w = tid >> 6, l = tid & 63;
    int ng = nt * 4 + w;

    // Q fragments in registers (hi/lo), 8 K-chunks of 32
    short8 qfh[8], qfl[8];
    {
        const u16* qbh = qh + (((size_t)b * 128 + ng) * 8 * 64 + l) * 8;
        const u16* qbl = ql + (((size_t)b * 128 + ng) * 8 * 64 + l) * 8;
        #pragma unroll
        for (int cc = 0; cc < 8; ++cc) {
            qfh[cc] = *(const short8*)(qbh + cc * 512);
            qfl[cc] = *(const short8*)(qbl + cc * 512);
        }
    }

    f32x4 O[16];
    #pragma unroll
    for (int cg = 0; cg < 16; ++cg) O[cg] = (f32x4){0.f, 0.f, 0.f, 0.f};
    float mrow[4] = {-1e30f, -1e30f, -1e30f, -1e30f};
    float lrow[4] = {0.f, 0.f, 0.f, 0.f};

    // each wave stages one 16KB buffer: w=0:KH w=1:KL w=2:VH w=3:VL
    const u16* src;
    {
        size_t toff = (size_t)b * 64 * 8192 + (size_t)l * 8;
        src = (w == 0) ? (kh + toff) : (w == 1) ? (kl + toff)
            : (w == 2) ? (vh + toff) : (vl + toff);
    }
    u16* stdst = &smem[w * 8192];

    for (int mc = 0; mc < 64; ++mc) {
        {
            const short8* s8 = (const short8*)(src + (size_t)mc * 8192);
            short8* d8 = (short8*)stdst;
            #pragma unroll
            for (int i = 0; i < 16; ++i) d8[i * 64 + l] = s8[i * 64];
        }
        __syncthreads();

        // S = Q^T K  (3-pass hi/lo)
        f32x4 s0v = (f32x4){0.f, 0.f, 0.f, 0.f};
        f32x4 s1v = (f32x4){0.f, 0.f, 0.f, 0.f};
        const short8* KH8 = (const short8*)&smem[0];
        const short8* KL8 = (const short8*)&smem[8192];
        #pragma unroll
        for (int cc = 0; cc < 8; ++cc) {
            short8 k0h = KH8[cc * 64 + l];
            short8 k0l = KL8[cc * 64 + l];
            short8 k1h = KH8[(8 + cc) * 64 + l];
            short8 k1l = KL8[(8 + cc) * 64 + l];
            s0v = mfma16(qfh[cc], k0h, s0v);
            s0v = mfma16(qfh[cc], k0l, s0v);
            s0v = mfma16(qfl[cc], k0h, s0v);
            s1v = mfma16(qfh[cc], k1h, s1v);
            s1v = mfma16(qfh[cc], k1l, s1v);
            s1v = mfma16(qfl[cc], k1h, s1v);
        }

        // online softmax (rows: 16 lanes sharing l>>4 hold cols; per-lane 4 rows)
        float tm[4], al[4], p0[4], p1[4], rs[4];
        #pragma unroll
        for (int r = 0; r < 4; ++r) tm[r] = fmaxf(s0v[r], s1v[r]);
        #pragma unroll
        for (int off = 1; off < 16; off <<= 1) {
            #pragma unroll
            for (int r = 0; r < 4; ++r) tm[r] = fmaxf(tm[r], __shfl_xor(tm[r], off));
        }
        #pragma unroll
        for (int r = 0; r < 4; ++r) {
            float mn = fmaxf(mrow[r], tm[r]);
            al[r] = exp2f((mrow[r] - mn) * L2E);
            mrow[r] = mn;
            p0[r] = exp2f((s0v[r] - mn) * L2E);
            p1[r] = exp2f((s1v[r] - mn) * L2E);
            rs[r] = p0[r] + p1[r];
        }
        #pragma unroll
        for (int off = 1; off < 16; off <<= 1) {
            #pragma unroll
            for (int r = 0; r < 4; ++r) rs[r] += __shfl_xor(rs[r], off);
        }
        #pragma unroll
        for (int r = 0; r < 4; ++r) lrow[r] = lrow[r] * al[r] + rs[r];

        // P -> hi/lo bf16, bounce through per-wave LDS into A-frag layout
        u16* PH = &smem[32768 + w * 512];
        u16* PL = &smem[34816 + w * 512];
        {
            int colm = l & 15, rowb = (l >> 4) * 4;
            #pragma unroll
            for (int mf = 0; mf < 2; ++mf) {
                int mloc = mf * 16 + colm;
                int lp = (mloc >> 3) * 16, j = mloc & 7;
                #pragma unroll
                for (int r = 0; r < 4; ++r) {
                    float pv = mf ? p1[r] : p0[r];
                    u16 h = f2bf(pv);
                    PH[(lp + rowb + r) * 8 + j] = h;
                    PL[(lp + rowb + r) * 8 + j] = f2bf(pv - bf2f(h));
                }
            }
        }

        // rescale O by alpha
        #pragma unroll
        for (int cg = 0; cg < 16; ++cg) {
            #pragma unroll
            for (int r = 0; r < 4; ++r) O[cg][r] *= al[r];
        }

        // O += P V  (3-pass hi/lo)
        short8 pah = *(const short8*)(PH + l * 8);
        short8 pal = *(const short8*)(PL + l * 8);
        const short8* VH8 = (const short8*)&smem[16384];
        const short8* VL8 = (const short8*)&smem[24576];
        #pragma unroll
        for (int cg = 0; cg < 16; ++cg) {
            short8 vvh = VH8[cg * 64 + l];
            short8 vvl = VL8[cg * 64 + l];
            O[cg] = mfma16(pah, vvh, O[cg]);
            O[cg] = mfma16(pah, vvl, O[cg]);
            O[cg] = mfma16(pal, vvh, O[cg]);
        }
        __syncthreads();
    }

    // normalize
    float inv[4];
    #pragma unroll
    for (int r = 0; r < 4; ++r) inv[r] = 1.f / lrow[r];
    #pragma unroll
    for (int cg = 0; cg < 16; ++cg) {
        #pragma unroll
        for (int r = 0; r < 4; ++r) O[cg][r] *= inv[r];
    }

    // fused final conv: write attn tile (hi/lo) to per-wave LDS in A-frag layout
    u16* OSH = &smem[w * 8192];
    u16* OSL = &smem[w * 8192 + 4096];
    {
        int colc = l & 15, rowb = (l >> 4) * 4;
        #pragma unroll
        for (int cg = 0; cg < 16; ++cg) {
            int c = cg * 16 + colc;
            int cc = c >> 5, lp = ((c >> 3) & 3) * 16, j = c & 7;
            #pragma unroll
            for (int r = 0; r < 4; ++r) {
                float z = O[cg][r];
                u16 h = f2bf(z);
                OSH[(cc * 64 + lp + rowb + r) * 8 + j] = h;
                OSL[(cc * 64 + lp + rowb + r) * 8 + j] = f2bf(z - bf2f(h));
            }
        }
    }

    short8 afh[8], afl[8];
    #pragma unroll
    for (int cc = 0; cc < 8; ++cc) {
        afh[cc] = *(const short8*)(OSH + (cc * 64 + l) * 8);
        afl[cc] = *(const short8*)(OSL + (cc * 64 + l) * 8);
    }

    #pragma unroll
    for (int og = 0; og < 8; ++og) {
        f32x4 a = (f32x4){0.f, 0.f, 0.f, 0.f};
        #pragma unroll
        for (int cc = 0; cc < 8; ++cc) {
            short8 bh = *(const short8*)(wfh + ((size_t)(og * 8 + cc) * 64 + l) * 8);
            short8 bl = *(const short8*)(wfl + ((size_t)(og * 8 + cc) * 64 + l) * 8);
            a = mfma16(afh[cc], bh, a);
            a = mfma16(afh[cc], bl, a);
            a = mfma16(afl[cc], bh, a);
        }
        int o = og * 16 + (l & 15);
        float sc = sf[o], tb = tf[o];
        #pragma unroll
        for (int r = 0; r < 4; ++r) {
            int n = ng * 16 + (l >> 4) * 4 + r;
            out[(size_t)b * COUT * N_ + (size_t)o * N_ + n] = fmaxf(fmaf(a[r], sc, tb), 0.f);
        }
    }
}

// ---------------------------------------------------------------------------
extern "C" void kernel_launch(void* const* d_in, const int* in_sizes, int n_in,
                              void* d_out, int out_size, void* d_ws, size_t ws_size,
                              hipStream_t stream)
{
    const float* x   = (const float*)d_in[0];
    const float* Wq  = (const float*)d_in[1];
    const float* Wk  = (const float*)d_in[2];
    const float* Wv  = (const float*)d_in[3];
    const float* Wf  = (const float*)d_in[4];
    const float* bnq = (const float*)d_in[5];
    const float* bnk = (const float*)d_in[6];
    const float* bnv = (const float*)d_in[7];
    const float* bnf = (const float*)d_in[8];
    float* out = (float*)d_out;

    const size_t NBUF = (size_t)B_ * N_ * C_;   // 8,388,608 u16 per buffer
    u16* qh  = (u16*)d_ws;
    u16* ql  = qh + NBUF;
    u16* kh  = ql + NBUF;
    u16* kl  = kh + NBUF;
    u16* vh  = kl + NBUF;
    u16* vl  = vh + NBUF;
    u16* wfh = vl + NBUF;           // 32768 u16
    u16* wfl = wfh + 32768;
    float* sf = (float*)(wfl + 32768);
    float* tf = sf + 128;
    // total ws usage ~96.1 MiB

    wf_prep<<<dim3(1), dim3(256), 0, stream>>>(Wf, bnf, wfh, wfl, sf, tf);
    stage_qkv<<<dim3(512), dim3(256), 0, stream>>>(x, Wq, Wk, Wv, bnq, bnk, bnv,
                                                   qh, ql, kh, kl, vh, vl);
    attn_fwd<<<dim3(512), dim3(256), 0, stream>>>(qh, ql, kh, kl, vh, vl,
                                                  wfh, wfl, sf, tf, out);
}

// Round 2
// 408.708 us; speedup vs baseline: 1.4730x; 1.4730x over previous
//
#include <hip/hip_runtime.h>

typedef __attribute__((ext_vector_type(4))) float f32x4;
typedef __attribute__((ext_vector_type(8))) short short8;
typedef __attribute__((ext_vector_type(4))) unsigned short us4;
typedef unsigned short u16;
typedef unsigned int u32;

#define B_   16
#define N_   2048
#define C_   256
#define CIN  131
#define COUT 128
#define L2E  1.44269504088896f

__device__ __forceinline__ u16 f2bf(float x) {
    u32 u = __float_as_uint(x);
    u32 r = (u + 0x7fffu + ((u >> 16) & 1u)) >> 16;
    return (u16)r;
}
__device__ __forceinline__ float bf2f(u16 h) {
    return __uint_as_float(((u32)h) << 16);
}

__device__ __forceinline__ f32x4 mfma16(short8 a, short8 b, f32x4 c) {
    return __builtin_amdgcn_mfma_f32_16x16x32_bf16(a, b, c, 0, 0, 0);
}

// ---------------------------------------------------------------------------
// Kernel 1: Wf -> fragment-major hi/lo bf16, plus folded BN scale/bias for bn_f
// ---------------------------------------------------------------------------
__global__ __launch_bounds__(256) void wf_prep(
    const float* __restrict__ Wf, const float* __restrict__ bnf,
    u16* __restrict__ wfh, u16* __restrict__ wfl,
    float* __restrict__ sf, float* __restrict__ tf)
{
    int t = threadIdx.x;
    for (int idx = t; idx < 8 * 8 * 64; idx += 256) {
        int og = idx >> 9;
        int cc = (idx >> 6) & 7;
        int l  = idx & 63;
        int o  = og * 16 + (l & 15);
        int c0 = cc * 32 + (l >> 4) * 8;
        #pragma unroll
        for (int j = 0; j < 8; ++j) {
            float f = Wf[o * 256 + c0 + j];
            u16 h = f2bf(f);
            wfh[(size_t)idx * 8 + j] = h;
            wfl[(size_t)idx * 8 + j] = f2bf(f - bf2f(h));
        }
    }
    if (t < COUT) {
        float g  = bnf[t];
        float be = bnf[128 + t];
        float mu = bnf[256 + t];
        float va = bnf[384 + t];
        float s = g * rsqrtf(va + 1e-5f);
        sf[t] = s;
        tf[t] = be - mu * s;
    }
}

// ---------------------------------------------------------------------------
// Kernel 2: QKV projection + BN + ReLU, fp32 vector math. (unchanged from R1)
// ---------------------------------------------------------------------------
__global__ __launch_bounds__(256, 2) void stage_qkv(
    const float* __restrict__ x,
    const float* __restrict__ Wq, const float* __restrict__ Wk, const float* __restrict__ Wv,
    const float* __restrict__ bnq, const float* __restrict__ bnk, const float* __restrict__ bnv,
    u16* __restrict__ qh, u16* __restrict__ ql,
    u16* __restrict__ kh, u16* __restrict__ kl,
    u16* __restrict__ vh, u16* __restrict__ vl)
{
    __shared__ __align__(16) float xs[CIN * 64];
    __shared__ __align__(16) float wt[CIN * 64];

    int b  = blockIdx.x >> 5;
    int n0 = (blockIdx.x & 31) * 64;
    int t  = threadIdx.x;
    int tc = t & 15, tr = t >> 4;

    {
        int col = tc * 4;
        for (int r = tr; r < CIN; r += 16) {
            f32x4 vx = *(const f32x4*)(x + ((size_t)b * CIN + r) * N_ + n0 + col);
            *(f32x4*)&xs[r * 64 + col] = vx;
        }
    }

    for (int chunk = 0; chunk < 12; ++chunk) {
        int which = chunk >> 2;
        int cbase = (chunk & 3) * 64;
        const float* W = (which == 0) ? Wq : (which == 1 ? Wk : Wv);

        __syncthreads();
        for (int idx = t; idx < 64 * CIN; idx += 256) {
            int r = idx & 63;
            int i = idx >> 6;
            wt[i * 64 + r] = W[(size_t)(cbase + r) * CIN + i];
        }
        __syncthreads();

        float acc[4][4];
        #pragma unroll
        for (int ii = 0; ii < 4; ++ii)
            #pragma unroll
            for (int jj = 0; jj < 4; ++jj) acc[ii][jj] = 0.f;

        for (int i = 0; i < CIN; ++i) {
            f32x4 wv = *(const f32x4*)&wt[i * 64 + tc * 4];
            f32x4 xv = *(const f32x4*)&xs[i * 64 + tr * 4];
            #pragma unroll
            for (int ii = 0; ii < 4; ++ii)
                #pragma unroll
                for (int jj = 0; jj < 4; ++jj)
                    acc[ii][jj] = fmaf(wv[ii], xv[jj], acc[ii][jj]);
        }

        const float* bn = (which == 0) ? bnq : (which == 1 ? bnk : bnv);
        int c0 = cbase + tc * 4;
        int nb = n0 + tr * 4;
        u16 hh[4][4], hl[4][4];
        #pragma unroll
        for (int ii = 0; ii < 4; ++ii) {
            int c = c0 + ii;
            float g  = bn[c];
            float be = bn[256 + c];
            float mu = bn[512 + c];
            float va = bn[768 + c];
            float s  = g * rsqrtf(va + 1e-5f);
            float tb = be - mu * s;
            #pragma unroll
            for (int jj = 0; jj < 4; ++jj) {
                float z = fmaxf(fmaf(acc[ii][jj], s, tb), 0.f);
                u16 h = f2bf(z);
                hh[ii][jj] = h;
                hl[ii][jj] = f2bf(z - bf2f(h));
            }
        }

        if (which < 2) {
            u16* dh = which ? kh : qh;
            u16* dl = which ? kl : ql;
            #pragma unroll
            for (int jj = 0; jj < 4; ++jj) {
                int n = nb + jj;
                size_t base;
                if (which == 0) {
                    base = ((((size_t)b * 128 + (n >> 4)) * 8 + (c0 >> 5)) * 64
                            + ((c0 >> 3) & 3) * 16 + (n & 15)) * 8 + (c0 & 7);
                } else {
                    base = (((((size_t)b * 64 + (n >> 5)) * 2 + ((n >> 4) & 1)) * 8 + (c0 >> 5)) * 64
                            + ((c0 >> 3) & 3) * 16 + (n & 15)) * 8 + (c0 & 7);
                }
                us4 v0 = { hh[0][jj], hh[1][jj], hh[2][jj], hh[3][jj] };
                us4 v1 = { hl[0][jj], hl[1][jj], hl[2][jj], hl[3][jj] };
                *(us4*)(dh + base) = v0;
                *(us4*)(dl + base) = v1;
            }
        } else {
            #pragma unroll
            for (int ii = 0; ii < 4; ++ii) {
                int c = c0 + ii;
                size_t base = ((((size_t)b * 64 + (nb >> 5)) * 16 + (c >> 4)) * 64
                               + ((nb >> 3) & 3) * 16 + (c & 15)) * 8 + (nb & 7);
                us4 v0 = { hh[ii][0], hh[ii][1], hh[ii][2], hh[ii][3] };
                us4 v1 = { hl[ii][0], hl[ii][1], hl[ii][2], hl[ii][3] };
                *(us4*)(vh + base) = v0;
                *(us4*)(vl + base) = v1;
            }
        }
    }
}

// ---------------------------------------------------------------------------
// Kernel 3: flash attention, register-prefetch double-pipeline (T14) +
// setprio around MFMA clusters (T5) + exact defer-rescale.
// Block: 256 threads = 4 waves; wave w owns 16 q-rows.
// LDS (72KB): KT_HI @0, KT_LO @8192, VT_HI @16384, VT_LO @24576,
//             PH[4][64][8] @32768, PL @34816  (u16 units)
// ---------------------------------------------------------------------------
__global__ __launch_bounds__(256, 2) void attn_fwd(
    const u16* __restrict__ qh, const u16* __restrict__ ql,
    const u16* __restrict__ kh, const u16* __restrict__ kl,
    const u16* __restrict__ vh, const u16* __restrict__ vl,
    const u16* __restrict__ wfh, const u16* __restrict__ wfl,
    const float* __restrict__ sf, const float* __restrict__ tf,
    float* __restrict__ out)
{
    __shared__ __align__(16) u16 smem[36864];

    int bid = blockIdx.x;
    int swz = (bid & 7) * 64 + (bid >> 3);   // XCD-chunked swizzle (bijective, 512 blocks)
    int b   = swz >> 5;
    int nt  = swz & 31;
    int tid = threadIdx.x;
    int w = tid >> 6, l = tid & 63;
    int ng = nt * 4 + w;

    // Q fragments in registers (hi/lo), 8 K-chunks of 32
    short8 qfh[8], qfl[8];
    {
        const u16* qbh = qh + (((size_t)b * 128 + ng) * 8 * 64 + l) * 8;
        const u16* qbl = ql + (((size_t)b * 128 + ng) * 8 * 64 + l) * 8;
        #pragma unroll
        for (int cc = 0; cc < 8; ++cc) {
            qfh[cc] = *(const short8*)(qbh + cc * 512);
            qfl[cc] = *(const short8*)(qbl + cc * 512);
        }
    }

    f32x4 O[16];
    #pragma unroll
    for (int cg = 0; cg < 16; ++cg) O[cg] = (f32x4){0.f, 0.f, 0.f, 0.f};
    float mrow[4] = {-1e30f, -1e30f, -1e30f, -1e30f};
    float lrow[4] = {0.f, 0.f, 0.f, 0.f};

    // each wave stages one 16KB buffer: w=0:KH w=1:KL w=2:VH w=3:VL
    const u16* src;
    {
        size_t toff = (size_t)b * 64 * 8192 + (size_t)l * 8;
        src = (w == 0) ? (kh + toff) : (w == 1) ? (kl + toff)
            : (w == 2) ? (vh + toff) : (vl + toff);
    }
    short8* d8 = (short8*)&smem[w * 8192];

    // prologue: prefetch tile 0 into registers
    short8 pf[16];
    {
        const short8* s8 = (const short8*)src;
        #pragma unroll
        for (int i = 0; i < 16; ++i) pf[i] = s8[i * 64];
    }

    for (int mc = 0; mc < 64; ++mc) {
        __syncthreads();                       // previous tile's readers done
        #pragma unroll
        for (int i = 0; i < 16; ++i) d8[i * 64 + l] = pf[i];
        if (mc < 63) {                         // issue next tile's loads; they fly
            const short8* s8 = (const short8*)(src + (size_t)(mc + 1) * 8192);
            #pragma unroll
            for (int i = 0; i < 16; ++i) pf[i] = s8[i * 64];
        }
        __syncthreads();                       // tile mc staged

        // S = Q^T K  (3-pass hi/lo)
        f32x4 s0v = (f32x4){0.f, 0.f, 0.f, 0.f};
        f32x4 s1v = (f32x4){0.f, 0.f, 0.f, 0.f};
        const short8* KH8 = (const short8*)&smem[0];
        const short8* KL8 = (const short8*)&smem[8192];
        __builtin_amdgcn_s_setprio(1);
        #pragma unroll
        for (int cc = 0; cc < 8; ++cc) {
            short8 k0h = KH8[cc * 64 + l];
            short8 k0l = KL8[cc * 64 + l];
            short8 k1h = KH8[(8 + cc) * 64 + l];
            short8 k1l = KL8[(8 + cc) * 64 + l];
            s0v = mfma16(qfh[cc], k0h, s0v);
            s0v = mfma16(qfh[cc], k0l, s0v);
            s0v = mfma16(qfl[cc], k0h, s0v);
            s1v = mfma16(qfh[cc], k1h, s1v);
            s1v = mfma16(qfh[cc], k1l, s1v);
            s1v = mfma16(qfl[cc], k1h, s1v);
        }
        __builtin_amdgcn_s_setprio(0);

        // online softmax: row max over the 32 new cols
        float tm[4];
        #pragma unroll
        for (int r = 0; r < 4; ++r) tm[r] = fmaxf(s0v[r], s1v[r]);
        #pragma unroll
        for (int off = 1; off < 16; off <<= 1) {
            #pragma unroll
            for (int r = 0; r < 4; ++r) tm[r] = fmaxf(tm[r], __shfl_xor(tm[r], off));
        }
        bool grow = false;
        #pragma unroll
        for (int r = 0; r < 4; ++r) grow = grow || (tm[r] > mrow[r]);
        if (__any(grow)) {                     // exact skip: al==1 when no growth
            #pragma unroll
            for (int r = 0; r < 4; ++r) {
                float mn = fmaxf(mrow[r], tm[r]);
                float al = exp2f((mrow[r] - mn) * L2E);
                mrow[r] = mn;
                lrow[r] *= al;
                #pragma unroll
                for (int cg = 0; cg < 16; ++cg) O[cg][r] *= al;
            }
        }
        float p0[4], p1[4], rs[4];
        #pragma unroll
        for (int r = 0; r < 4; ++r) {
            p0[r] = exp2f((s0v[r] - mrow[r]) * L2E);
            p1[r] = exp2f((s1v[r] - mrow[r]) * L2E);
            rs[r] = p0[r] + p1[r];
        }
        #pragma unroll
        for (int off = 1; off < 16; off <<= 1) {
            #pragma unroll
            for (int r = 0; r < 4; ++r) rs[r] += __shfl_xor(rs[r], off);
        }
        #pragma unroll
        for (int r = 0; r < 4; ++r) lrow[r] += rs[r];

        // P -> hi/lo bf16 via per-wave LDS bounce into A-frag layout
        u16* PH = &smem[32768 + w * 512];
        u16* PL = &smem[34816 + w * 512];
        {
            int colm = l & 15, rowb = (l >> 4) * 4;
            #pragma unroll
            for (int mf = 0; mf < 2; ++mf) {
                int mloc = mf * 16 + colm;
                int lp = (mloc >> 3) * 16, j = mloc & 7;
                #pragma unroll
                for (int r = 0; r < 4; ++r) {
                    float pv = mf ? p1[r] : p0[r];
                    u16 h = f2bf(pv);
                    PH[(lp + rowb + r) * 8 + j] = h;
                    PL[(lp + rowb + r) * 8 + j] = f2bf(pv - bf2f(h));
                }
            }
        }

        // O += P V  (3-pass hi/lo)
        short8 pah = *(const short8*)(PH + l * 8);
        short8 pal = *(const short8*)(PL + l * 8);
        const short8* VH8 = (const short8*)&smem[16384];
        const short8* VL8 = (const short8*)&smem[24576];
        __builtin_amdgcn_s_setprio(1);
        #pragma unroll
        for (int cg = 0; cg < 16; ++cg) {
            short8 vvh = VH8[cg * 64 + l];
            short8 vvl = VL8[cg * 64 + l];
            O[cg] = mfma16(pah, vvh, O[cg]);
            O[cg] = mfma16(pah, vvl, O[cg]);
            O[cg] = mfma16(pal, vvh, O[cg]);
        }
        __builtin_amdgcn_s_setprio(0);
    }
    __syncthreads();                           // staging regions reused below

    // normalize
    float inv[4];
    #pragma unroll
    for (int r = 0; r < 4; ++r) inv[r] = 1.f / lrow[r];
    #pragma unroll
    for (int cg = 0; cg < 16; ++cg) {
        #pragma unroll
        for (int r = 0; r < 4; ++r) O[cg][r] *= inv[r];
    }

    // fused final conv: write attn tile (hi/lo) to per-wave LDS in A-frag layout
    u16* OSH = &smem[w * 8192];
    u16* OSL = &smem[w * 8192 + 4096];
    {
        int colc = l & 15, rowb = (l >> 4) * 4;
        #pragma unroll
        for (int cg = 0; cg < 16; ++cg) {
            int c = cg * 16 + colc;
            int cc = c >> 5, lp = ((c >> 3) & 3) * 16, j = c & 7;
            #pragma unroll
            for (int r = 0; r < 4; ++r) {
                float z = O[cg][r];
                u16 h = f2bf(z);
                OSH[(cc * 64 + lp + rowb + r) * 8 + j] = h;
                OSL[(cc * 64 + lp + rowb + r) * 8 + j] = f2bf(z - bf2f(h));
            }
        }
    }

    short8 afh[8], afl[8];
    #pragma unroll
    for (int cc = 0; cc < 8; ++cc) {
        afh[cc] = *(const short8*)(OSH + (cc * 64 + l) * 8);
        afl[cc] = *(const short8*)(OSL + (cc * 64 + l) * 8);
    }

    #pragma unroll
    for (int og = 0; og < 8; ++og) {
        f32x4 a = (f32x4){0.f, 0.f, 0.f, 0.f};
        #pragma unroll
        for (int cc = 0; cc < 8; ++cc) {
            short8 bh = *(const short8*)(wfh + ((size_t)(og * 8 + cc) * 64 + l) * 8);
            short8 bl = *(const short8*)(wfl + ((size_t)(og * 8 + cc) * 64 + l) * 8);
            a = mfma16(afh[cc], bh, a);
            a = mfma16(afh[cc], bl, a);
            a = mfma16(afl[cc], bh, a);
        }
        int o = og * 16 + (l & 15);
        float sc = sf[o], tb = tf[o];
        #pragma unroll
        for (int r = 0; r < 4; ++r) {
            int n = ng * 16 + (l >> 4) * 4 + r;
            out[(size_t)b * COUT * N_ + (size_t)o * N_ + n] = fmaxf(fmaf(a[r], sc, tb), 0.f);
        }
    }
}

// ---------------------------------------------------------------------------
extern "C" void kernel_launch(void* const* d_in, const int* in_sizes, int n_in,
                              void* d_out, int out_size, void* d_ws, size_t ws_size,
                              hipStream_t stream)
{
    const float* x   = (const float*)d_in[0];
    const float* Wq  = (const float*)d_in[1];
    const float* Wk  = (const float*)d_in[2];
    const float* Wv  = (const float*)d_in[3];
    const float* Wf  = (const float*)d_in[4];
    const float* bnq = (const float*)d_in[5];
    const float* bnk = (const float*)d_in[6];
    const float* bnv = (const float*)d_in[7];
    const float* bnf = (const float*)d_in[8];
    float* out = (float*)d_out;

    const size_t NBUF = (size_t)B_ * N_ * C_;   // 8,388,608 u16 per buffer
    u16* qh  = (u16*)d_ws;
    u16* ql  = qh + NBUF;
    u16* kh  = ql + NBUF;
    u16* kl  = kh + NBUF;
    u16* vh  = kl + NBUF;
    u16* vl  = vh + NBUF;
    u16* wfh = vl + NBUF;           // 32768 u16
    u16* wfl = wfh + 32768;
    float* sf = (float*)(wfl + 32768);
    float* tf = sf + 128;

    wf_prep<<<dim3(1), dim3(256), 0, stream>>>(Wf, bnf, wfh, wfl, sf, tf);
    stage_qkv<<<dim3(512), dim3(256), 0, stream>>>(x, Wq, Wk, Wv, bnq, bnk, bnv,
                                                   qh, ql, kh, kl, vh, vl);
    attn_fwd<<<dim3(512), dim3(256), 0, stream>>>(qh, ql, kh, kl, vh, vl,
                                                  wfh, wfl, sf, tf, out);
}

// Round 3
// 349.251 us; speedup vs baseline: 1.7237x; 1.1702x over previous
//
#include <hip/hip_runtime.h>

typedef __attribute__((ext_vector_type(4))) float f32x4;
typedef __attribute__((ext_vector_type(8))) short short8;
typedef __attribute__((ext_vector_type(4))) unsigned short us4;
typedef unsigned short u16;
typedef unsigned int u32;
typedef _Float16 f16;
typedef __attribute__((ext_vector_type(8))) f16 f16x8;

#define B_   16
#define N_   2048
#define C_   256
#define CIN  131
#define COUT 128
#define L2E  1.44269504088896f

__device__ __forceinline__ u16 f2bf(float x) {
    u32 u = __float_as_uint(x);
    u32 r = (u + 0x7fffu + ((u >> 16) & 1u)) >> 16;
    return (u16)r;
}
__device__ __forceinline__ float bf2f(u16 h) {
    return __uint_as_float(((u32)h) << 16);
}
__device__ __forceinline__ u16 f2h(float x) {
    union { f16 h; u16 u; } c; c.h = (f16)x; return c.u;
}
__device__ __forceinline__ float h2f(u16 u) {
    union { u16 u; f16 h; } c; c.u = u; return (float)c.h;
}

__device__ __forceinline__ f32x4 mfma16(short8 a, short8 b, f32x4 c) {
    return __builtin_amdgcn_mfma_f32_16x16x32_bf16(a, b, c, 0, 0, 0);
}
__device__ __forceinline__ f32x4 mfma16h(f16x8 a, f16x8 b, f32x4 c) {
    return __builtin_amdgcn_mfma_f32_16x16x32_f16(a, b, c, 0, 0, 0);
}

typedef __attribute__((address_space(1))) const unsigned int gu32;
typedef __attribute__((address_space(3))) unsigned int lu32;
// dst must be wave-uniform; HW writes dst + lane*16B. src is per-lane.
__device__ __forceinline__ void gl_lds16(const u16* g, u16* l) {
    __builtin_amdgcn_global_load_lds((gu32*)g, (lu32*)l, 16, 0, 0);
}

// ---------------------------------------------------------------------------
// Kernel 1: Wf -> fragment-major hi/lo FP16, plus folded BN scale/bias
// ---------------------------------------------------------------------------
__global__ __launch_bounds__(256) void wf_prep(
    const float* __restrict__ Wf, const float* __restrict__ bnf,
    u16* __restrict__ wfh, u16* __restrict__ wfl,
    float* __restrict__ sf, float* __restrict__ tf)
{
    int t = threadIdx.x;
    for (int idx = t; idx < 8 * 8 * 64; idx += 256) {
        int og = idx >> 9;
        int cc = (idx >> 6) & 7;
        int l  = idx & 63;
        int o  = og * 16 + (l & 15);
        int c0 = cc * 32 + (l >> 4) * 8;
        (void)og; (void)cc;
        #pragma unroll
        for (int j = 0; j < 8; ++j) {
            float f = Wf[o * 256 + c0 + j];
            u16 h = f2h(f);
            wfh[(size_t)idx * 8 + j] = h;
            wfl[(size_t)idx * 8 + j] = f2h(f - h2f(h));
        }
    }
    if (t < COUT) {
        float g  = bnf[t];
        float be = bnf[128 + t];
        float mu = bnf[256 + t];
        float va = bnf[384 + t];
        float s = g * rsqrtf(va + 1e-5f);
        sf[t] = s;
        tf[t] = be - mu * s;
    }
}

// ---------------------------------------------------------------------------
// Kernel 2: QKV projection + BN + ReLU, fp32 vector math.
// q/k: hi/lo bf16 fragment-major (unchanged). v: SINGLE fp16 fragment-major.
// ---------------------------------------------------------------------------
__global__ __launch_bounds__(256, 2) void stage_qkv(
    const float* __restrict__ x,
    const float* __restrict__ Wq, const float* __restrict__ Wk, const float* __restrict__ Wv,
    const float* __restrict__ bnq, const float* __restrict__ bnk, const float* __restrict__ bnv,
    u16* __restrict__ qh, u16* __restrict__ ql,
    u16* __restrict__ kh, u16* __restrict__ kl,
    u16* __restrict__ vf)
{
    __shared__ __align__(16) float xs[CIN * 64];
    __shared__ __align__(16) float wt[CIN * 64];

    int b  = blockIdx.x >> 5;
    int n0 = (blockIdx.x & 31) * 64;
    int t  = threadIdx.x;
    int tc = t & 15, tr = t >> 4;

    {
        int col = tc * 4;
        for (int r = tr; r < CIN; r += 16) {
            f32x4 vx = *(const f32x4*)(x + ((size_t)b * CIN + r) * N_ + n0 + col);
            *(f32x4*)&xs[r * 64 + col] = vx;
        }
    }

    for (int chunk = 0; chunk < 12; ++chunk) {
        int which = chunk >> 2;
        int cbase = (chunk & 3) * 64;
        const float* W = (which == 0) ? Wq : (which == 1 ? Wk : Wv);

        __syncthreads();
        for (int idx = t; idx < 64 * CIN; idx += 256) {
            int r = idx & 63;
            int i = idx >> 6;
            wt[i * 64 + r] = W[(size_t)(cbase + r) * CIN + i];
        }
        __syncthreads();

        float acc[4][4];
        #pragma unroll
        for (int ii = 0; ii < 4; ++ii)
            #pragma unroll
            for (int jj = 0; jj < 4; ++jj) acc[ii][jj] = 0.f;

        for (int i = 0; i < CIN; ++i) {
            f32x4 wv = *(const f32x4*)&wt[i * 64 + tc * 4];
            f32x4 xv = *(const f32x4*)&xs[i * 64 + tr * 4];
            #pragma unroll
            for (int ii = 0; ii < 4; ++ii)
                #pragma unroll
                for (int jj = 0; jj < 4; ++jj)
                    acc[ii][jj] = fmaf(wv[ii], xv[jj], acc[ii][jj]);
        }

        const float* bn = (which == 0) ? bnq : (which == 1 ? bnk : bnv);
        int c0 = cbase + tc * 4;
        int nb = n0 + tr * 4;
        float z[4][4];
        #pragma unroll
        for (int ii = 0; ii < 4; ++ii) {
            int c = c0 + ii;
            float g  = bn[c];
            float be = bn[256 + c];
            float mu = bn[512 + c];
            float va = bn[768 + c];
            float s  = g * rsqrtf(va + 1e-5f);
            float tb = be - mu * s;
            #pragma unroll
            for (int jj = 0; jj < 4; ++jj)
                z[ii][jj] = fmaxf(fmaf(acc[ii][jj], s, tb), 0.f);
        }

        if (which < 2) {
            u16* dh = which ? kh : qh;
            u16* dl = which ? kl : ql;
            #pragma unroll
            for (int jj = 0; jj < 4; ++jj) {
                int n = nb + jj;
                size_t base;
                if (which == 0) {
                    base = ((((size_t)b * 128 + (n >> 4)) * 8 + (c0 >> 5)) * 64
                            + ((c0 >> 3) & 3) * 16 + (n & 15)) * 8 + (c0 & 7);
                } else {
                    base = (((((size_t)b * 64 + (n >> 5)) * 2 + ((n >> 4) & 1)) * 8 + (c0 >> 5)) * 64
                            + ((c0 >> 3) & 3) * 16 + (n & 15)) * 8 + (c0 & 7);
                }
                u16 hh0 = f2bf(z[0][jj]), hh1 = f2bf(z[1][jj]);
                u16 hh2 = f2bf(z[2][jj]), hh3 = f2bf(z[3][jj]);
                us4 v0 = { hh0, hh1, hh2, hh3 };
                us4 v1 = { f2bf(z[0][jj] - bf2f(hh0)), f2bf(z[1][jj] - bf2f(hh1)),
                           f2bf(z[2][jj] - bf2f(hh2)), f2bf(z[3][jj] - bf2f(hh3)) };
                *(us4*)(dh + base) = v0;
                *(us4*)(dl + base) = v1;
            }
        } else {
            #pragma unroll
            for (int ii = 0; ii < 4; ++ii) {
                int c = c0 + ii;
                size_t base = ((((size_t)b * 64 + (nb >> 5)) * 16 + (c >> 4)) * 64
                               + ((nb >> 3) & 3) * 16 + (c & 15)) * 8 + (nb & 7);
                us4 v0 = { f2h(z[ii][0]), f2h(z[ii][1]), f2h(z[ii][2]), f2h(z[ii][3]) };
                *(us4*)(vf + base) = v0;
            }
        }
    }
}

// ---------------------------------------------------------------------------
// Kernel 3: flash attention.
// QK: bf16 hi/lo 3-pass (proven). PV: fp16 single-pass. Final conv: fp16 2-pass.
// Staging: global_load_lds (16B), K single-buffered, V double-buffered;
// loads for tile mc+1 issued after barrier A, drained at barrier B (hidden
// under PV compute).
// LDS (68KB u16 idx): KH @0, KL @8192, VF0 @16384, VF1 @24576, PH @32768(+w*512)
// ---------------------------------------------------------------------------
__global__ __launch_bounds__(256, 2) void attn_fwd(
    const u16* __restrict__ qh, const u16* __restrict__ ql,
    const u16* __restrict__ kh, const u16* __restrict__ kl,
    const u16* __restrict__ vf,
    const u16* __restrict__ wfh, const u16* __restrict__ wfl,
    const float* __restrict__ sf, const float* __restrict__ tf,
    float* __restrict__ out)
{
    __shared__ __align__(16) u16 smem[34816];

    int bid = blockIdx.x;
    int swz = (bid & 7) * 64 + (bid >> 3);   // XCD-chunked swizzle (bijective, 512 blocks)
    int b   = swz >> 5;
    int nt  = swz & 31;
    int tid = threadIdx.x;
    int w = tid >> 6, l = tid & 63;
    int ng = nt * 4 + w;

    const u16* khb = kh + (size_t)b * 64 * 8192;
    const u16* klb = kl + (size_t)b * 64 * 8192;
    const u16* vfb = vf + (size_t)b * 64 * 8192;

    // stage rows 12w..12w+11 of [KH(16) | KL(16) | VF(16)] for tile mc
    auto stage12 = [&](int mc, int vbase) {
        size_t mo = (size_t)mc * 8192;
        #pragma unroll
        for (int i = 0; i < 12; ++i) {
            int r = w * 12 + i;
            const u16* g; int dst;
            if (r < 16)      { g = khb + mo + r * 512;        dst = r * 512; }
            else if (r < 32) { g = klb + mo + (r - 16) * 512; dst = 8192 + (r - 16) * 512; }
            else             { g = vfb + mo + (r - 32) * 512; dst = vbase + (r - 32) * 512; }
            gl_lds16(g + l * 8, &smem[dst]);
        }
    };

    // Q fragments in registers (hi/lo), 8 K-chunks of 32
    short8 qfh[8], qfl[8];
    {
        const u16* qbh = qh + (((size_t)b * 128 + ng) * 8 * 64 + l) * 8;
        const u16* qbl = ql + (((size_t)b * 128 + ng) * 8 * 64 + l) * 8;
        #pragma unroll
        for (int cc = 0; cc < 8; ++cc) {
            qfh[cc] = *(const short8*)(qbh + cc * 512);
            qfl[cc] = *(const short8*)(qbl + cc * 512);
        }
    }

    f32x4 O[16];
    #pragma unroll
    for (int cg = 0; cg < 16; ++cg) O[cg] = (f32x4){0.f, 0.f, 0.f, 0.f};
    float mrow[4] = {-1e30f, -1e30f, -1e30f, -1e30f};
    float lrow[4] = {0.f, 0.f, 0.f, 0.f};

    // prologue: stage tile 0 (K + V->buf0)
    stage12(0, 16384);
    asm volatile("s_waitcnt vmcnt(0)" ::: "memory");
    __syncthreads();

    u16* PH = &smem[32768 + w * 512];

    for (int mc = 0; mc < 64; ++mc) {
        // ---- S = Q^T K (3-pass hi/lo bf16) ----
        f32x4 s0v = (f32x4){0.f, 0.f, 0.f, 0.f};
        f32x4 s1v = (f32x4){0.f, 0.f, 0.f, 0.f};
        const short8* KH8 = (const short8*)&smem[0];
        const short8* KL8 = (const short8*)&smem[8192];
        __builtin_amdgcn_s_setprio(1);
        #pragma unroll
        for (int cc = 0; cc < 8; ++cc) {
            short8 k0h = KH8[cc * 64 + l];
            short8 k0l = KL8[cc * 64 + l];
            short8 k1h = KH8[(8 + cc) * 64 + l];
            short8 k1l = KL8[(8 + cc) * 64 + l];
            s0v = mfma16(qfh[cc], k0h, s0v);
            s0v = mfma16(qfh[cc], k0l, s0v);
            s0v = mfma16(qfl[cc], k0h, s0v);
            s1v = mfma16(qfh[cc], k1h, s1v);
            s1v = mfma16(qfh[cc], k1l, s1v);
            s1v = mfma16(qfl[cc], k1h, s1v);
        }
        __builtin_amdgcn_s_setprio(0);

        // ---- online softmax ----
        float tm[4];
        #pragma unroll
        for (int r = 0; r < 4; ++r) tm[r] = fmaxf(s0v[r], s1v[r]);
        #pragma unroll
        for (int off = 1; off < 16; off <<= 1) {
            #pragma unroll
            for (int r = 0; r < 4; ++r) tm[r] = fmaxf(tm[r], __shfl_xor(tm[r], off));
        }
        bool grow = false;
        #pragma unroll
        for (int r = 0; r < 4; ++r) grow = grow || (tm[r] > mrow[r]);
        if (__any(grow)) {                     // exact skip: al==1 when no growth
            #pragma unroll
            for (int r = 0; r < 4; ++r) {
                float mn = fmaxf(mrow[r], tm[r]);
                float al = exp2f((mrow[r] - mn) * L2E);
                mrow[r] = mn;
                lrow[r] *= al;
                #pragma unroll
                for (int cg = 0; cg < 16; ++cg) O[cg][r] *= al;
            }
        }
        u16 p0u[4], p1u[4];
        float rs[4];
        #pragma unroll
        for (int r = 0; r < 4; ++r) {
            p0u[r] = f2h(exp2f((s0v[r] - mrow[r]) * L2E));
            p1u[r] = f2h(exp2f((s1v[r] - mrow[r]) * L2E));
            rs[r] = h2f(p0u[r]) + h2f(p1u[r]);   // denominator matches fp16 numerator mass
        }
        #pragma unroll
        for (int off = 1; off < 16; off <<= 1) {
            #pragma unroll
            for (int r = 0; r < 4; ++r) rs[r] += __shfl_xor(rs[r], off);
        }
        #pragma unroll
        for (int r = 0; r < 4; ++r) lrow[r] += rs[r];

        // P (fp16) -> per-wave LDS bounce into A-frag layout
        {
            int colm = l & 15, rowb = (l >> 4) * 4;
            #pragma unroll
            for (int mf = 0; mf < 2; ++mf) {
                int mloc = mf * 16 + colm;
                int lp = (mloc >> 3) * 16, j = mloc & 7;
                #pragma unroll
                for (int r = 0; r < 4; ++r)
                    PH[(lp + rowb + r) * 8 + j] = mf ? p1u[r] : p0u[r];
            }
        }

        __syncthreads();                       // barrier A: K(mc) & V[(mc+1)&1] readers done
        if (mc < 63) stage12(mc + 1, 16384 + ((mc + 1) & 1) * 8192);

        // ---- O += P V (fp16 single-pass) ----
        f16x8 pa = *(const f16x8*)(PH + l * 8);
        const f16x8* VF8 = (const f16x8*)&smem[16384 + (mc & 1) * 8192];
        __builtin_amdgcn_s_setprio(1);
        #pragma unroll
        for (int cg = 0; cg < 16; ++cg) {
            f16x8 vv = VF8[cg * 64 + l];
            O[cg] = mfma16h(pa, vv, O[cg]);
        }
        __builtin_amdgcn_s_setprio(0);

        asm volatile("s_waitcnt vmcnt(0)" ::: "memory");
        __syncthreads();                       // barrier B: tile mc+1 staged & published
    }

    // normalize
    float inv[4];
    #pragma unroll
    for (int r = 0; r < 4; ++r) inv[r] = 1.f / lrow[r];
    #pragma unroll
    for (int cg = 0; cg < 16; ++cg) {
        #pragma unroll
        for (int r = 0; r < 4; ++r) O[cg][r] *= inv[r];
    }

    // fused final conv: attn tile -> fp16 A-frags via per-wave LDS region
    u16* OS = &smem[w * 4096];
    {
        int colc = l & 15, rowb = (l >> 4) * 4;
        #pragma unroll
        for (int cg = 0; cg < 16; ++cg) {
            int c = cg * 16 + colc;
            int cc = c >> 5, lp = ((c >> 3) & 3) * 16, j = c & 7;
            #pragma unroll
            for (int r = 0; r < 4; ++r)
                OS[(cc * 64 + lp + rowb + r) * 8 + j] = f2h(O[cg][r]);
        }
    }

    f16x8 af[8];
    #pragma unroll
    for (int cc = 0; cc < 8; ++cc)
        af[cc] = *(const f16x8*)(OS + (cc * 64 + l) * 8);

    #pragma unroll
    for (int og = 0; og < 8; ++og) {
        f32x4 a = (f32x4){0.f, 0.f, 0.f, 0.f};
        #pragma unroll
        for (int cc = 0; cc < 8; ++cc) {
            f16x8 bh = *(const f16x8*)(wfh + ((size_t)(og * 8 + cc) * 64 + l) * 8);
            f16x8 bl = *(const f16x8*)(wfl + ((size_t)(og * 8 + cc) * 64 + l) * 8);
            a = mfma16h(af[cc], bh, a);
            a = mfma16h(af[cc], bl, a);
        }
        int o = og * 16 + (l & 15);
        float sc = sf[o], tb = tf[o];
        #pragma unroll
        for (int r = 0; r < 4; ++r) {
            int n = ng * 16 + (l >> 4) * 4 + r;
            out[(size_t)b * COUT * N_ + (size_t)o * N_ + n] = fmaxf(fmaf(a[r], sc, tb), 0.f);
        }
    }
}

// ---------------------------------------------------------------------------
extern "C" void kernel_launch(void* const* d_in, const int* in_sizes, int n_in,
                              void* d_out, int out_size, void* d_ws, size_t ws_size,
                              hipStream_t stream)
{
    const float* x   = (const float*)d_in[0];
    const float* Wq  = (const float*)d_in[1];
    const float* Wk  = (const float*)d_in[2];
    const float* Wv  = (const float*)d_in[3];
    const float* Wf  = (const float*)d_in[4];
    const float* bnq = (const float*)d_in[5];
    const float* bnk = (const float*)d_in[6];
    const float* bnv = (const float*)d_in[7];
    const float* bnf = (const float*)d_in[8];
    float* out = (float*)d_out;

    const size_t NBUF = (size_t)B_ * N_ * C_;   // 8,388,608 u16 per buffer
    u16* qh  = (u16*)d_ws;
    u16* ql  = qh + NBUF;
    u16* kh  = ql + NBUF;
    u16* kl  = kh + NBUF;
    u16* vf  = kl + NBUF;
    u16* wfh = vf + NBUF;           // 32768 u16 (fp16 hi)
    u16* wfl = wfh + 32768;         // fp16 lo
    float* sf = (float*)(wfl + 32768);
    float* tf = sf + 128;
    // total ws usage ~84 MiB

    wf_prep<<<dim3(1), dim3(256), 0, stream>>>(Wf, bnf, wfh, wfl, sf, tf);
    stage_qkv<<<dim3(512), dim3(256), 0, stream>>>(x, Wq, Wk, Wv, bnq, bnk, bnv,
                                                   qh, ql, kh, kl, vf);
    attn_fwd<<<dim3(512), dim3(256), 0, stream>>>(qh, ql, kh, kl, vf,
                                                  wfh, wfl, sf, tf, out);
}

// Round 4
// 256.114 us; speedup vs baseline: 2.3506x; 1.3637x over previous
//
#include <hip/hip_runtime.h>

typedef __attribute__((ext_vector_type(4))) float f32x4;
typedef __attribute__((ext_vector_type(8))) short short8;
typedef __attribute__((ext_vector_type(4))) unsigned short us4;
typedef unsigned short u16;
typedef unsigned int u32;
typedef _Float16 f16;
typedef __attribute__((ext_vector_type(8))) f16 f16x8;

#define B_   16
#define N_   2048
#define C_   256
#define CIN  131
#define COUT 128
#define L2E  1.44269504088896f

__device__ __forceinline__ u16 f2bf(float x) {
    u32 u = __float_as_uint(x);
    u32 r = (u + 0x7fffu + ((u >> 16) & 1u)) >> 16;
    return (u16)r;
}
__device__ __forceinline__ float bf2f(u16 h) {
    return __uint_as_float(((u32)h) << 16);
}
__device__ __forceinline__ u16 f2h(float x) {
    union { f16 h; u16 u; } c; c.h = (f16)x; return c.u;
}
__device__ __forceinline__ float h2f(u16 u) {
    union { u16 u; f16 h; } c; c.u = u; return (float)c.h;
}

__device__ __forceinline__ f32x4 mfma16(short8 a, short8 b, f32x4 c) {
    return __builtin_amdgcn_mfma_f32_16x16x32_bf16(a, b, c, 0, 0, 0);
}
__device__ __forceinline__ f32x4 mfma16h(f16x8 a, f16x8 b, f32x4 c) {
    return __builtin_amdgcn_mfma_f32_16x16x32_f16(a, b, c, 0, 0, 0);
}

typedef __attribute__((address_space(1))) const unsigned int gu32;
typedef __attribute__((address_space(3))) unsigned int lu32;
// dst must be wave-uniform; HW writes dst + lane*16B. src is per-lane.
__device__ __forceinline__ void gl_lds16(const u16* g, u16* l) {
    __builtin_amdgcn_global_load_lds((gu32*)g, (lu32*)l, 16, 0, 0);
}

// ---------------------------------------------------------------------------
// Kernel 1: weight prep.
//  wA: Wq/Wk/Wv -> hi/lo bf16 A-frags, K padded 131->160.
//      wA[((m*16+og)*5+cc)*64 + l][j] = W_m[og*16+(l&15)][cc*32+(l>>4)*8+j]
//  wf: Wf -> hi/lo fp16 A-frag-major (as before).
//  BN folds: sqkv/tqkv[m*256+c], sf/tf[o].
// grid 76 x 256
// ---------------------------------------------------------------------------
__global__ __launch_bounds__(256) void w_prep(
    const float* __restrict__ Wq, const float* __restrict__ Wk,
    const float* __restrict__ Wv, const float* __restrict__ Wf,
    const float* __restrict__ bnq, const float* __restrict__ bnk,
    const float* __restrict__ bnv, const float* __restrict__ bnf,
    u16* __restrict__ wAh, u16* __restrict__ wAl,
    u16* __restrict__ wfh, u16* __restrict__ wfl,
    float* __restrict__ sqkv, float* __restrict__ tqkv,
    float* __restrict__ sf, float* __restrict__ tf)
{
    int t = threadIdx.x, l = t & 63;
    int g = blockIdx.x * 4 + (t >> 6);
    if (g < 240) {
        int m = g / 80, rem = g % 80, og = rem / 5, cc = rem % 5;
        const float* W = (m == 0) ? Wq : (m == 1) ? Wk : Wv;
        int o = og * 16 + (l & 15);
        size_t base = ((size_t)g * 64 + l) * 8;
        #pragma unroll
        for (int j = 0; j < 8; ++j) {
            int k = cc * 32 + (l >> 4) * 8 + j;
            float f = (k < CIN) ? W[o * CIN + k] : 0.f;
            u16 h = f2bf(f);
            wAh[base + j] = h;
            wAl[base + j] = f2bf(f - bf2f(h));
        }
    } else if (g < 304) {
        int u = g - 240;
        int o = (u >> 3) * 16 + (l & 15);
        int c0 = (u & 7) * 32 + (l >> 4) * 8;
        size_t base = ((size_t)u * 64 + l) * 8;
        #pragma unroll
        for (int j = 0; j < 8; ++j) {
            float f = Wf[o * 256 + c0 + j];
            u16 h = f2h(f);
            wfh[base + j] = h;
            wfl[base + j] = f2h(f - h2f(h));
        }
    }
    if (blockIdx.x == 0) {
        if (t < 256) {
            #pragma unroll
            for (int m = 0; m < 3; ++m) {
                const float* bn = (m == 0) ? bnq : (m == 1) ? bnk : bnv;
                float s = bn[t] * rsqrtf(bn[768 + t] + 1e-5f);
                sqkv[m * 256 + t] = s;
                tqkv[m * 256 + t] = bn[256 + t] - bn[512 + t] * s;
            }
        }
        if (t < 128) {
            float s = bnf[t] * rsqrtf(bnf[384 + t] + 1e-5f);
            sf[t] = s;
            tf[t] = bnf[128 + t] - bnf[256 + t] * s;
        }
    }
}

// ---------------------------------------------------------------------------
// Kernel 2: QKV projection via MFMA hi/lo bf16 (3-pass = fp32-accurate).
// grid 1536 = (m, b, nt); block 256 thr = 4 waves; wave w owns out-ch [64w,64w+64).
// x-tile [131][64] transposed into LDS xs[n][k] (padded to 164, zero-fill k>=131),
// packed per-cc into hi/lo B-frags in-register.
// Outputs q/k (hi/lo bf16) and v (fp16) in the attention fragment layouts.
// ---------------------------------------------------------------------------
__global__ __launch_bounds__(256) void qkv_proj(
    const float* __restrict__ x,
    const u16* __restrict__ wAh, const u16* __restrict__ wAl,
    const float* __restrict__ sqkv, const float* __restrict__ tqkv,
    u16* __restrict__ qh, u16* __restrict__ ql,
    u16* __restrict__ kh, u16* __restrict__ kl, u16* __restrict__ vf)
{
    __shared__ __align__(16) float xs[64][164];

    int bid = blockIdx.x;
    int m  = bid >> 9;
    int r9 = bid & 511;
    int b = r9 >> 5, nt = r9 & 31;
    int t = threadIdx.x;
    int w = t >> 6, l = t & 63;
    int n0 = nt * 64;

    // load + transpose x tile -> xs[n][k]
    {
        int nb = (t & 15) * 4;
        for (int k = (t >> 4); k < CIN; k += 16) {
            f32x4 v = *(const f32x4*)(x + ((size_t)b * CIN + k) * N_ + n0 + nb);
            xs[nb + 0][k] = v[0]; xs[nb + 1][k] = v[1];
            xs[nb + 2][k] = v[2]; xs[nb + 3][k] = v[3];
        }
        for (int idx = t; idx < 64 * 29; idx += 256) {
            int n = idx / 29, k = CIN + idx % 29;
            xs[n][k] = 0.f;
        }
    }
    __syncthreads();

    f32x4 acc[4][4];
    #pragma unroll
    for (int og = 0; og < 4; ++og)
        #pragma unroll
        for (int njg = 0; njg < 4; ++njg) acc[og][njg] = (f32x4){0.f, 0.f, 0.f, 0.f};

    for (int cc = 0; cc < 5; ++cc) {
        // B-frags (x) hi/lo from LDS
        short8 xbh[4], xbl[4];
        #pragma unroll
        for (int njg = 0; njg < 4; ++njg) {
            int n = njg * 16 + (l & 15);
            int k0 = cc * 32 + (l >> 4) * 8;
            f32x4 u0 = *(const f32x4*)&xs[n][k0];
            f32x4 u1 = *(const f32x4*)&xs[n][k0 + 4];
            u16 hh[8], ll[8];
            #pragma unroll
            for (int jj = 0; jj < 4; ++jj) {
                hh[jj] = f2bf(u0[jj]);     ll[jj] = f2bf(u0[jj] - bf2f(hh[jj]));
                hh[4 + jj] = f2bf(u1[jj]); ll[4 + jj] = f2bf(u1[jj] - bf2f(hh[4 + jj]));
            }
            short8 vh_, vl_;
            #pragma unroll
            for (int jj = 0; jj < 8; ++jj) { vh_[jj] = (short)hh[jj]; vl_[jj] = (short)ll[jj]; }
            xbh[njg] = vh_; xbl[njg] = vl_;
        }
        // A-frags (W) hi/lo from global (hot in L2)
        #pragma unroll
        for (int og = 0; og < 4; ++og) {
            size_t base = (((size_t)(m * 16 + w * 4 + og) * 5 + cc) * 64 + l) * 8;
            short8 ah = *(const short8*)(wAh + base);
            short8 al4 = *(const short8*)(wAl + base);
            #pragma unroll
            for (int njg = 0; njg < 4; ++njg) {
                acc[og][njg] = mfma16(ah,  xbh[njg], acc[og][njg]);
                acc[og][njg] = mfma16(ah,  xbl[njg], acc[og][njg]);
                acc[og][njg] = mfma16(al4, xbh[njg], acc[og][njg]);
            }
        }
    }

    // epilogue: BN + ReLU + pack to attention fragment layouts
    #pragma unroll
    for (int og = 0; og < 4; ++og) {
        int cb = (w * 4 + og) * 16 + (l >> 4) * 4;   // c = cb + r
        f32x4 sv = *(const f32x4*)(sqkv + m * 256 + cb);
        f32x4 tv = *(const f32x4*)(tqkv + m * 256 + cb);
        #pragma unroll
        for (int njg = 0; njg < 4; ++njg) {
            int n = n0 + njg * 16 + (l & 15);
            float z[4];
            #pragma unroll
            for (int r = 0; r < 4; ++r)
                z[r] = fmaxf(fmaf(acc[og][njg][r], sv[r], tv[r]), 0.f);
            if (m < 2) {
                u16 h0 = f2bf(z[0]), h1 = f2bf(z[1]), h2 = f2bf(z[2]), h3 = f2bf(z[3]);
                us4 hi4 = { h0, h1, h2, h3 };
                us4 lo4 = { f2bf(z[0] - bf2f(h0)), f2bf(z[1] - bf2f(h1)),
                            f2bf(z[2] - bf2f(h2)), f2bf(z[3] - bf2f(h3)) };
                size_t base;
                if (m == 0)
                    base = ((((size_t)b * 128 + (n >> 4)) * 8 + (cb >> 5)) * 64
                            + ((cb >> 3) & 3) * 16 + (n & 15)) * 8 + (cb & 7);
                else
                    base = (((((size_t)b * 64 + (n >> 5)) * 2 + ((n >> 4) & 1)) * 8 + (cb >> 5)) * 64
                            + ((cb >> 3) & 3) * 16 + (n & 15)) * 8 + (cb & 7);
                *(us4*)((m ? kh : qh) + base) = hi4;
                *(us4*)((m ? kl : ql) + base) = lo4;
            } else {
                size_t base = ((((size_t)b * 64 + (n >> 5)) * 16 + (cb >> 4)) * 64
                               + ((n >> 3) & 3) * 16 + ((l >> 4) * 4)) * 8 + (n & 7);
                #pragma unroll
                for (int r = 0; r < 4; ++r)
                    vf[base + (size_t)r * 8] = f2h(z[r]);
            }
        }
    }
}

// ---------------------------------------------------------------------------
// Kernel 3: flash attention.
// QK: bf16 hi/lo 3-pass. PV: fp16 single-pass. Final conv: fp16 2-pass.
// V staged at loop TOP (dbuf, long cover); K staged post-barrier-A (single buf).
// Defer-rescale THR=8 (exact compensation via lrow from rounded P).
// LDS (68KB u16): KH @0, KL @8192, VF0 @16384, VF1 @24576, PH @32768(+w*512)
// ---------------------------------------------------------------------------
__global__ __launch_bounds__(256, 2) void attn_fwd(
    const u16* __restrict__ qh, const u16* __restrict__ ql,
    const u16* __restrict__ kh, const u16* __restrict__ kl,
    const u16* __restrict__ vf,
    const u16* __restrict__ wfh, const u16* __restrict__ wfl,
    const float* __restrict__ sf, const float* __restrict__ tf,
    float* __restrict__ out)
{
    __shared__ __align__(16) u16 smem[34816];

    int bid = blockIdx.x;
    int swz = (bid & 7) * 64 + (bid >> 3);   // XCD-chunked swizzle (bijective, 512 blocks)
    int b   = swz >> 5;
    int nt  = swz & 31;
    int tid = threadIdx.x;
    int w = tid >> 6, l = tid & 63;
    int ng = nt * 4 + w;

    const u16* khb = kh + (size_t)b * 64 * 8192;
    const u16* klb = kl + (size_t)b * 64 * 8192;
    const u16* vfb = vf + (size_t)b * 64 * 8192;

    auto stageK = [&](int mc) {               // 32 rows (KH16+KL16), 8 per wave
        size_t mo = (size_t)mc * 8192;
        #pragma unroll
        for (int i = 0; i < 8; ++i) {
            int r = w * 8 + i;
            const u16* g; int dst;
            if (r < 16) { g = khb + mo + r * 512;        dst = r * 512; }
            else        { g = klb + mo + (r - 16) * 512; dst = 8192 + (r - 16) * 512; }
            gl_lds16(g + l * 8, &smem[dst]);
        }
    };
    auto stageV = [&](int mc, int vbase) {    // 16 rows, 4 per wave
        size_t mo = (size_t)mc * 8192;
        #pragma unroll
        for (int i = 0; i < 4; ++i) {
            int r = w * 4 + i;
            gl_lds16(vfb + mo + r * 512 + l * 8, &smem[vbase + r * 512]);
        }
    };

    // Q fragments in registers (hi/lo), 8 K-chunks of 32
    short8 qfh[8], qfl[8];
    {
        const u16* qbh = qh + (((size_t)b * 128 + ng) * 8 * 64 + l) * 8;
        const u16* qbl = ql + (((size_t)b * 128 + ng) * 8 * 64 + l) * 8;
        #pragma unroll
        for (int cc = 0; cc < 8; ++cc) {
            qfh[cc] = *(const short8*)(qbh + cc * 512);
            qfl[cc] = *(const short8*)(qbl + cc * 512);
        }
    }

    f32x4 O[16];
    #pragma unroll
    for (int cg = 0; cg < 16; ++cg) O[cg] = (f32x4){0.f, 0.f, 0.f, 0.f};
    float mrow[4] = {-1e30f, -1e30f, -1e30f, -1e30f};
    float lrow[4] = {0.f, 0.f, 0.f, 0.f};

    // prologue
    stageK(0);
    stageV(0, 16384);
    asm volatile("s_waitcnt vmcnt(0)" ::: "memory");
    __syncthreads();

    u16* PH = &smem[32768 + w * 512];

    for (int mc = 0; mc < 64; ++mc) {
        if (mc < 63) stageV(mc + 1, 16384 + ((mc + 1) & 1) * 8192);  // long cover

        // ---- S = Q^T K (3-pass hi/lo bf16) ----
        f32x4 s0v = (f32x4){0.f, 0.f, 0.f, 0.f};
        f32x4 s1v = (f32x4){0.f, 0.f, 0.f, 0.f};
        const short8* KH8 = (const short8*)&smem[0];
        const short8* KL8 = (const short8*)&smem[8192];
        __builtin_amdgcn_s_setprio(1);
        #pragma unroll
        for (int cc = 0; cc < 8; ++cc) {
            short8 k0h = KH8[cc * 64 + l];
            short8 k0l = KL8[cc * 64 + l];
            short8 k1h = KH8[(8 + cc) * 64 + l];
            short8 k1l = KL8[(8 + cc) * 64 + l];
            s0v = mfma16(qfh[cc], k0h, s0v);
            s0v = mfma16(qfh[cc], k0l, s0v);
            s0v = mfma16(qfl[cc], k0h, s0v);
            s1v = mfma16(qfh[cc], k1h, s1v);
            s1v = mfma16(qfh[cc], k1l, s1v);
            s1v = mfma16(qfl[cc], k1h, s1v);
        }
        __builtin_amdgcn_s_setprio(0);

        // ---- online softmax (defer-rescale, THR=8) ----
        float tm[4];
        #pragma unroll
        for (int r = 0; r < 4; ++r) tm[r] = fmaxf(s0v[r], s1v[r]);
        #pragma unroll
        for (int off = 1; off < 16; off <<= 1) {
            #pragma unroll
            for (int r = 0; r < 4; ++r) tm[r] = fmaxf(tm[r], __shfl_xor(tm[r], off));
        }
        bool need = false;
        #pragma unroll
        for (int r = 0; r < 4; ++r) need = need || (tm[r] > mrow[r] + 8.f);
        if (__any(need)) {
            #pragma unroll
            for (int r = 0; r < 4; ++r) {
                float mn = fmaxf(mrow[r], tm[r]);
                float al = exp2f((mrow[r] - mn) * L2E);
                mrow[r] = mn;
                lrow[r] *= al;
                #pragma unroll
                for (int cg = 0; cg < 16; ++cg) O[cg][r] *= al;
            }
        }
        u16 p0u[4], p1u[4];
        float rs[4];
        #pragma unroll
        for (int r = 0; r < 4; ++r) {
            p0u[r] = f2h(exp2f((s0v[r] - mrow[r]) * L2E));
            p1u[r] = f2h(exp2f((s1v[r] - mrow[r]) * L2E));
            rs[r] = h2f(p0u[r]) + h2f(p1u[r]);   // denominator matches fp16 numerator mass
        }
        #pragma unroll
        for (int off = 1; off < 16; off <<= 1) {
            #pragma unroll
            for (int r = 0; r < 4; ++r) rs[r] += __shfl_xor(rs[r], off);
        }
        #pragma unroll
        for (int r = 0; r < 4; ++r) lrow[r] += rs[r];

        // P (fp16) -> per-wave LDS bounce into A-frag layout
        {
            int colm = l & 15, rowb = (l >> 4) * 4;
            #pragma unroll
            for (int mf = 0; mf < 2; ++mf) {
                int mloc = mf * 16 + colm;
                int lp = (mloc >> 3) * 16, j = mloc & 7;
                #pragma unroll
                for (int r = 0; r < 4; ++r)
                    PH[(lp + rowb + r) * 8 + j] = mf ? p1u[r] : p0u[r];
            }
        }

        __syncthreads();                       // barrier A: K(mc) readers done
        if (mc < 63) stageK(mc + 1);

        // ---- O += P V (fp16 single-pass) ----
        f16x8 pa = *(const f16x8*)(PH + l * 8);
        const f16x8* VF8 = (const f16x8*)&smem[16384 + (mc & 1) * 8192];
        __builtin_amdgcn_s_setprio(1);
        #pragma unroll
        for (int cg = 0; cg < 16; ++cg) {
            f16x8 vv = VF8[cg * 64 + l];
            O[cg] = mfma16h(pa, vv, O[cg]);
        }
        __builtin_amdgcn_s_setprio(0);

        asm volatile("s_waitcnt vmcnt(0)" ::: "memory");
        __syncthreads();                       // barrier B: tile mc+1 staged
    }

    // normalize
    float inv[4];
    #pragma unroll
    for (int r = 0; r < 4; ++r) inv[r] = 1.f / lrow[r];
    #pragma unroll
    for (int cg = 0; cg < 16; ++cg) {
        #pragma unroll
        for (int r = 0; r < 4; ++r) O[cg][r] *= inv[r];
    }

    // fused final conv: attn tile -> fp16 A-frags via per-wave LDS region
    u16* OS = &smem[w * 4096];
    {
        int colc = l & 15, rowb = (l >> 4) * 4;
        #pragma unroll
        for (int cg = 0; cg < 16; ++cg) {
            int c = cg * 16 + colc;
            int cc = c >> 5, lp = ((c >> 3) & 3) * 16, j = c & 7;
            #pragma unroll
            for (int r = 0; r < 4; ++r)
                OS[(cc * 64 + lp + rowb + r) * 8 + j] = f2h(O[cg][r]);
        }
    }

    f16x8 af[8];
    #pragma unroll
    for (int cc = 0; cc < 8; ++cc)
        af[cc] = *(const f16x8*)(OS + (cc * 64 + l) * 8);

    #pragma unroll
    for (int og = 0; og < 8; ++og) {
        f32x4 a = (f32x4){0.f, 0.f, 0.f, 0.f};
        #pragma unroll
        for (int cc = 0; cc < 8; ++cc) {
            f16x8 bh = *(const f16x8*)(wfh + ((size_t)(og * 8 + cc) * 64 + l) * 8);
            f16x8 bl = *(const f16x8*)(wfl + ((size_t)(og * 8 + cc) * 64 + l) * 8);
            a = mfma16h(af[cc], bh, a);
            a = mfma16h(af[cc], bl, a);
        }
        int o = og * 16 + (l & 15);
        float sc = sf[o], tb = tf[o];
        #pragma unroll
        for (int r = 0; r < 4; ++r) {
            int n = ng * 16 + (l >> 4) * 4 + r;
            out[(size_t)b * COUT * N_ + (size_t)o * N_ + n] = fmaxf(fmaf(a[r], sc, tb), 0.f);
        }
    }
}

// ---------------------------------------------------------------------------
extern "C" void kernel_launch(void* const* d_in, const int* in_sizes, int n_in,
                              void* d_out, int out_size, void* d_ws, size_t ws_size,
                              hipStream_t stream)
{
    const float* x   = (const float*)d_in[0];
    const float* Wq  = (const float*)d_in[1];
    const float* Wk  = (const float*)d_in[2];
    const float* Wv  = (const float*)d_in[3];
    const float* Wf  = (const float*)d_in[4];
    const float* bnq = (const float*)d_in[5];
    const float* bnk = (const float*)d_in[6];
    const float* bnv = (const float*)d_in[7];
    const float* bnf = (const float*)d_in[8];
    float* out = (float*)d_out;

    const size_t NBUF = (size_t)B_ * N_ * C_;   // 8,388,608 u16 per buffer
    u16* qh  = (u16*)d_ws;
    u16* ql  = qh + NBUF;
    u16* kh  = ql + NBUF;
    u16* kl  = kh + NBUF;
    u16* vf  = kl + NBUF;
    u16* wfh = vf + NBUF;           // 32768 u16 (fp16 hi)
    u16* wfl = wfh + 32768;         // fp16 lo
    u16* wAh = wfl + 32768;         // 245760... (3*16*5*64*8 = 122880 u16)
    u16* wAl = wAh + 122880;
    float* sqkv = (float*)(wAl + 122880);
    float* tqkv = sqkv + 768;
    float* sf   = tqkv + 768;
    float* tf   = sf + 128;
    // total ws ~85 MiB

    w_prep<<<dim3(76), dim3(256), 0, stream>>>(Wq, Wk, Wv, Wf, bnq, bnk, bnv, bnf,
                                               wAh, wAl, wfh, wfl, sqkv, tqkv, sf, tf);
    qkv_proj<<<dim3(1536), dim3(256), 0, stream>>>(x, wAh, wAl, sqkv, tqkv,
                                                   qh, ql, kh, kl, vf);
    attn_fwd<<<dim3(512), dim3(256), 0, stream>>>(qh, ql, kh, kl, vf,
                                                  wfh, wfl, sf, tf, out);
}

// Round 5
// 241.250 us; speedup vs baseline: 2.4954x; 1.0616x over previous
//
#include <hip/hip_runtime.h>

typedef __attribute__((ext_vector_type(4))) float f32x4;
typedef __attribute__((ext_vector_type(8))) short short8;
typedef __attribute__((ext_vector_type(4))) unsigned short us4;
typedef unsigned short u16;
typedef unsigned int u32;
typedef _Float16 f16;
typedef __attribute__((ext_vector_type(8))) f16 f16x8;

#define B_   16
#define N_   2048
#define C_   256
#define CIN  131
#define COUT 128
#define L2E  1.44269504088896f

__device__ __forceinline__ u16 f2bf(float x) {
    u32 u = __float_as_uint(x);
    u32 r = (u + 0x7fffu + ((u >> 16) & 1u)) >> 16;
    return (u16)r;
}
__device__ __forceinline__ float bf2f(u16 h) {
    return __uint_as_float(((u32)h) << 16);
}
__device__ __forceinline__ u16 f2h(float x) {
    union { f16 h; u16 u; } c; c.h = (f16)x; return c.u;
}
__device__ __forceinline__ float h2f(u16 u) {
    union { u16 u; f16 h; } c; c.u = u; return (float)c.h;
}

__device__ __forceinline__ f32x4 mfma16(short8 a, short8 b, f32x4 c) {
    return __builtin_amdgcn_mfma_f32_16x16x32_bf16(a, b, c, 0, 0, 0);
}
__device__ __forceinline__ f32x4 mfma16h(f16x8 a, f16x8 b, f32x4 c) {
    return __builtin_amdgcn_mfma_f32_16x16x32_f16(a, b, c, 0, 0, 0);
}

typedef __attribute__((address_space(1))) const unsigned int gu32;
typedef __attribute__((address_space(3))) unsigned int lu32;
// dst must be wave-uniform; HW writes dst + lane*16B. src is per-lane.
__device__ __forceinline__ void gl_lds16(const u16* g, u16* l) {
    __builtin_amdgcn_global_load_lds((gu32*)g, (lu32*)l, 16, 0, 0);
}

// ---------------------------------------------------------------------------
// Kernel 1: weight prep (unchanged from R4).
//  wA: Wq/Wk/Wv -> hi/lo bf16 A-frags, K padded 131->160.
//  wf: Wf -> hi/lo fp16 B-frag-major (k=c, col=o).
//  BN folds: sqkv/tqkv[m*256+c], sf/tf[o].
// ---------------------------------------------------------------------------
__global__ __launch_bounds__(256) void w_prep(
    const float* __restrict__ Wq, const float* __restrict__ Wk,
    const float* __restrict__ Wv, const float* __restrict__ Wf,
    const float* __restrict__ bnq, const float* __restrict__ bnk,
    const float* __restrict__ bnv, const float* __restrict__ bnf,
    u16* __restrict__ wAh, u16* __restrict__ wAl,
    u16* __restrict__ wfh, u16* __restrict__ wfl,
    float* __restrict__ sqkv, float* __restrict__ tqkv,
    float* __restrict__ sf, float* __restrict__ tf)
{
    int t = threadIdx.x, l = t & 63;
    int g = blockIdx.x * 4 + (t >> 6);
    if (g < 240) {
        int m = g / 80, rem = g % 80, og = rem / 5, cc = rem % 5;
        const float* W = (m == 0) ? Wq : (m == 1) ? Wk : Wv;
        int o = og * 16 + (l & 15);
        size_t base = ((size_t)g * 64 + l) * 8;
        #pragma unroll
        for (int j = 0; j < 8; ++j) {
            int k = cc * 32 + (l >> 4) * 8 + j;
            float f = (k < CIN) ? W[o * CIN + k] : 0.f;
            u16 h = f2bf(f);
            wAh[base + j] = h;
            wAl[base + j] = f2bf(f - bf2f(h));
        }
    } else if (g < 304) {
        int u = g - 240;
        int o = (u >> 3) * 16 + (l & 15);
        int c0 = (u & 7) * 32 + (l >> 4) * 8;
        size_t base = ((size_t)u * 64 + l) * 8;
        #pragma unroll
        for (int j = 0; j < 8; ++j) {
            float f = Wf[o * 256 + c0 + j];
            u16 h = f2h(f);
            wfh[base + j] = h;
            wfl[base + j] = f2h(f - h2f(h));
        }
    }
    if (blockIdx.x == 0) {
        if (t < 256) {
            #pragma unroll
            for (int m = 0; m < 3; ++m) {
                const float* bn = (m == 0) ? bnq : (m == 1) ? bnk : bnv;
                float s = bn[t] * rsqrtf(bn[768 + t] + 1e-5f);
                sqkv[m * 256 + t] = s;
                tqkv[m * 256 + t] = bn[256 + t] - bn[512 + t] * s;
            }
        }
        if (t < 128) {
            float s = bnf[t] * rsqrtf(bnf[384 + t] + 1e-5f);
            sf[t] = s;
            tf[t] = bnf[128 + t] - bnf[256 + t] * s;
        }
    }
}

// ---------------------------------------------------------------------------
// Kernel 2: QKV projection via MFMA hi/lo bf16 (3-pass = fp32-accurate).
// q/k: hi/lo bf16 attention layouts (unchanged).
// v: fp16 A-frag layout for the VW GEMM: vt[b][n>>4][c>>5][l][j] with
//    row=m=n=(l&15), k=c=((l>>4)*8+j within 32)  — same index formula as q.
// ---------------------------------------------------------------------------
__global__ __launch_bounds__(256) void qkv_proj(
    const float* __restrict__ x,
    const u16* __restrict__ wAh, const u16* __restrict__ wAl,
    const float* __restrict__ sqkv, const float* __restrict__ tqkv,
    u16* __restrict__ qh, u16* __restrict__ ql,
    u16* __restrict__ kh, u16* __restrict__ kl, u16* __restrict__ vt)
{
    __shared__ __align__(16) float xs[64][164];

    int bid = blockIdx.x;
    int m  = bid >> 9;
    int r9 = bid & 511;
    int b = r9 >> 5, nt = r9 & 31;
    int t = threadIdx.x;
    int w = t >> 6, l = t & 63;
    int n0 = nt * 64;

    {
        int nb = (t & 15) * 4;
        for (int k = (t >> 4); k < CIN; k += 16) {
            f32x4 v = *(const f32x4*)(x + ((size_t)b * CIN + k) * N_ + n0 + nb);
            xs[nb + 0][k] = v[0]; xs[nb + 1][k] = v[1];
            xs[nb + 2][k] = v[2]; xs[nb + 3][k] = v[3];
        }
        for (int idx = t; idx < 64 * 29; idx += 256) {
            int n = idx / 29, k = CIN + idx % 29;
            xs[n][k] = 0.f;
        }
    }
    __syncthreads();

    f32x4 acc[4][4];
    #pragma unroll
    for (int og = 0; og < 4; ++og)
        #pragma unroll
        for (int njg = 0; njg < 4; ++njg) acc[og][njg] = (f32x4){0.f, 0.f, 0.f, 0.f};

    for (int cc = 0; cc < 5; ++cc) {
        short8 xbh[4], xbl[4];
        #pragma unroll
        for (int njg = 0; njg < 4; ++njg) {
            int n = njg * 16 + (l & 15);
            int k0 = cc * 32 + (l >> 4) * 8;
            f32x4 u0 = *(const f32x4*)&xs[n][k0];
            f32x4 u1 = *(const f32x4*)&xs[n][k0 + 4];
            u16 hh[8], ll[8];
            #pragma unroll
            for (int jj = 0; jj < 4; ++jj) {
                hh[jj] = f2bf(u0[jj]);     ll[jj] = f2bf(u0[jj] - bf2f(hh[jj]));
                hh[4 + jj] = f2bf(u1[jj]); ll[4 + jj] = f2bf(u1[jj] - bf2f(hh[4 + jj]));
            }
            short8 vh_, vl_;
            #pragma unroll
            for (int jj = 0; jj < 8; ++jj) { vh_[jj] = (short)hh[jj]; vl_[jj] = (short)ll[jj]; }
            xbh[njg] = vh_; xbl[njg] = vl_;
        }
        #pragma unroll
        for (int og = 0; og < 4; ++og) {
            size_t base = (((size_t)(m * 16 + w * 4 + og) * 5 + cc) * 64 + l) * 8;
            short8 ah  = *(const short8*)(wAh + base);
            short8 al4 = *(const short8*)(wAl + base);
            #pragma unroll
            for (int njg = 0; njg < 4; ++njg) {
                acc[og][njg] = mfma16(ah,  xbh[njg], acc[og][njg]);
                acc[og][njg] = mfma16(ah,  xbl[njg], acc[og][njg]);
                acc[og][njg] = mfma16(al4, xbh[njg], acc[og][njg]);
            }
        }
    }

    #pragma unroll
    for (int og = 0; og < 4; ++og) {
        int cb = (w * 4 + og) * 16 + (l >> 4) * 4;
        f32x4 sv = *(const f32x4*)(sqkv + m * 256 + cb);
        f32x4 tv = *(const f32x4*)(tqkv + m * 256 + cb);
        #pragma unroll
        for (int njg = 0; njg < 4; ++njg) {
            int n = n0 + njg * 16 + (l & 15);
            float z[4];
            #pragma unroll
            for (int r = 0; r < 4; ++r)
                z[r] = fmaxf(fmaf(acc[og][njg][r], sv[r], tv[r]), 0.f);
            size_t base = ((((size_t)b * 128 + (n >> 4)) * 8 + (cb >> 5)) * 64
                           + ((cb >> 3) & 3) * 16 + (n & 15)) * 8 + (cb & 7);
            if (m < 2) {
                if (m == 1)
                    base = (((((size_t)b * 64 + (n >> 5)) * 2 + ((n >> 4) & 1)) * 8 + (cb >> 5)) * 64
                            + ((cb >> 3) & 3) * 16 + (n & 15)) * 8 + (cb & 7);
                u16 h0 = f2bf(z[0]), h1 = f2bf(z[1]), h2 = f2bf(z[2]), h3 = f2bf(z[3]);
                us4 hi4 = { h0, h1, h2, h3 };
                us4 lo4 = { f2bf(z[0] - bf2f(h0)), f2bf(z[1] - bf2f(h1)),
                            f2bf(z[2] - bf2f(h2)), f2bf(z[3] - bf2f(h3)) };
                *(us4*)((m ? kh : qh) + base) = hi4;
                *(us4*)((m ? kl : ql) + base) = lo4;
            } else {
                us4 v0 = { f2h(z[0]), f2h(z[1]), f2h(z[2]), f2h(z[3]) };
                *(us4*)(vt + base) = v0;
            }
        }
    }
}

// ---------------------------------------------------------------------------
// Kernel 2b: VW = V^T · Wf  (fp16 out, B-frag layout for PV).
// grid 256 = (b, mt); block 4 waves; wave w owns o-frags {2w, 2w+1}.
// vw[b][m>>5][og][l][j] = VW[m = (m>>5)*32 + (l>>4)*8 + j][o = og*16 + (l&15)]
// ---------------------------------------------------------------------------
__global__ __launch_bounds__(256) void vw_proj(
    const u16* __restrict__ vt,
    const u16* __restrict__ wfh, const u16* __restrict__ wfl,
    u16* __restrict__ vw)
{
    int bid = blockIdx.x;
    int b = bid >> 4, mt = bid & 15;
    int t = threadIdx.x, w = t >> 6, l = t & 63;

    f32x4 acc[2][8];
    #pragma unroll
    for (int oi = 0; oi < 2; ++oi)
        #pragma unroll
        for (int mg = 0; mg < 8; ++mg) acc[oi][mg] = (f32x4){0.f, 0.f, 0.f, 0.f};

    for (int cc = 0; cc < 8; ++cc) {
        f16x8 vtf[8];
        #pragma unroll
        for (int mg = 0; mg < 8; ++mg)
            vtf[mg] = *(const f16x8*)(vt + ((((size_t)b * 128 + mt * 8 + mg) * 8 + cc) * 64 + l) * 8);
        #pragma unroll
        for (int oi = 0; oi < 2; ++oi) {
            int og = w * 2 + oi;
            f16x8 bh = *(const f16x8*)(wfh + (((size_t)og * 8 + cc) * 64 + l) * 8);
            f16x8 bl = *(const f16x8*)(wfl + (((size_t)og * 8 + cc) * 64 + l) * 8);
            #pragma unroll
            for (int mg = 0; mg < 8; ++mg) {
                acc[oi][mg] = mfma16h(vtf[mg], bh, acc[oi][mg]);
                acc[oi][mg] = mfma16h(vtf[mg], bl, acc[oi][mg]);
            }
        }
    }

    #pragma unroll
    for (int oi = 0; oi < 2; ++oi) {
        int og = w * 2 + oi;
        int ol = l & 15;
        #pragma unroll
        for (int mg = 0; mg < 8; ++mg) {
            #pragma unroll
            for (int r = 0; r < 4; ++r) {
                int mm = mt * 128 + mg * 16 + (l >> 4) * 4 + r;
                size_t idx = ((((size_t)b * 64 + (mm >> 5)) * 8 + og) * 64
                              + ((mm >> 3) & 3) * 16 + ol) * 8 + (mm & 7);
                vw[idx] = f2h(acc[oi][mg][r]);
            }
        }
    }
}

// ---------------------------------------------------------------------------
// Kernel 3: flash attention with VW fusion (final conv pre-folded into V).
// QK: bf16 hi/lo 3-pass. PV: P·VW fp16, 8 MFMA. Out written directly.
// LDS (52KB u16 idx): KH @0, KL @8192, VW0 @16384, VW1 @20480, PH @24576+w*512
// 3 blocks/CU (12 waves) — occupancy is the round's lever.
// ---------------------------------------------------------------------------
__global__ __launch_bounds__(256, 3) void attn_fwd(
    const u16* __restrict__ qh, const u16* __restrict__ ql,
    const u16* __restrict__ kh, const u16* __restrict__ kl,
    const u16* __restrict__ vw,
    const float* __restrict__ sf, const float* __restrict__ tf,
    float* __restrict__ out)
{
    __shared__ __align__(16) u16 smem[26624];

    int bid = blockIdx.x;
    int swz = (bid & 7) * 64 + (bid >> 3);   // XCD-chunked swizzle (bijective, 512 blocks)
    int b   = swz >> 5;
    int nt  = swz & 31;
    int tid = threadIdx.x;
    int w = tid >> 6, l = tid & 63;
    int ng = nt * 4 + w;

    const u16* khb = kh + (size_t)b * 64 * 8192;
    const u16* klb = kl + (size_t)b * 64 * 8192;
    const u16* vwb = vw + (size_t)b * 64 * 4096;

    auto stageK = [&](int mc) {               // 32 rows (KH16+KL16), 8 per wave
        size_t mo = (size_t)mc * 8192;
        #pragma unroll
        for (int i = 0; i < 8; ++i) {
            int r = w * 8 + i;
            const u16* g; int dst;
            if (r < 16) { g = khb + mo + r * 512;        dst = r * 512; }
            else        { g = klb + mo + (r - 16) * 512; dst = 8192 + (r - 16) * 512; }
            gl_lds16(g + l * 8, &smem[dst]);
        }
    };
    auto stageVW = [&](int mc, int vbase) {   // 8 rows of 1KB, 2 per wave
        size_t mo = (size_t)mc * 4096;
        #pragma unroll
        for (int i = 0; i < 2; ++i) {
            int r = w * 2 + i;
            gl_lds16(vwb + mo + r * 512 + l * 8, &smem[vbase + r * 512]);
        }
    };

    // Q fragments in registers (hi/lo), 8 K-chunks of 32
    short8 qfh[8], qfl[8];
    {
        const u16* qbh = qh + (((size_t)b * 128 + ng) * 8 * 64 + l) * 8;
        const u16* qbl = ql + (((size_t)b * 128 + ng) * 8 * 64 + l) * 8;
        #pragma unroll
        for (int cc = 0; cc < 8; ++cc) {
            qfh[cc] = *(const short8*)(qbh + cc * 512);
            qfl[cc] = *(const short8*)(qbl + cc * 512);
        }
    }

    f32x4 O[8];
    #pragma unroll
    for (int og = 0; og < 8; ++og) O[og] = (f32x4){0.f, 0.f, 0.f, 0.f};
    float mrow[4] = {-1e30f, -1e30f, -1e30f, -1e30f};
    float lrow[4] = {0.f, 0.f, 0.f, 0.f};

    // prologue
    stageK(0);
    stageVW(0, 16384);
    asm volatile("s_waitcnt vmcnt(0)" ::: "memory");
    __syncthreads();

    u16* PH = &smem[24576 + w * 512];

    for (int mc = 0; mc < 64; ++mc) {
        if (mc < 63) stageVW(mc + 1, 16384 + ((mc + 1) & 1) * 4096);

        // ---- S = Q^T K (3-pass hi/lo bf16) ----
        f32x4 s0v = (f32x4){0.f, 0.f, 0.f, 0.f};
        f32x4 s1v = (f32x4){0.f, 0.f, 0.f, 0.f};
        const short8* KH8 = (const short8*)&smem[0];
        const short8* KL8 = (const short8*)&smem[8192];
        __builtin_amdgcn_s_setprio(1);
        #pragma unroll
        for (int cc = 0; cc < 8; ++cc) {
            short8 k0h = KH8[cc * 64 + l];
            short8 k0l = KL8[cc * 64 + l];
            short8 k1h = KH8[(8 + cc) * 64 + l];
            short8 k1l = KL8[(8 + cc) * 64 + l];
            s0v = mfma16(qfh[cc], k0h, s0v);
            s0v = mfma16(qfh[cc], k0l, s0v);
            s0v = mfma16(qfl[cc], k0h, s0v);
            s1v = mfma16(qfh[cc], k1h, s1v);
            s1v = mfma16(qfh[cc], k1l, s1v);
            s1v = mfma16(qfl[cc], k1h, s1v);
        }
        __builtin_amdgcn_s_setprio(0);

        __syncthreads();                       // barrier A: K(mc) readers done
        if (mc < 63) stageK(mc + 1);           // K latency covered by softmax+PV

        // ---- online softmax (defer-rescale, THR=8) ----
        float tm[4];
        #pragma unroll
        for (int r = 0; r < 4; ++r) tm[r] = fmaxf(s0v[r], s1v[r]);
        #pragma unroll
        for (int off = 1; off < 16; off <<= 1) {
            #pragma unroll
            for (int r = 0; r < 4; ++r) tm[r] = fmaxf(tm[r], __shfl_xor(tm[r], off));
        }
        bool need = false;
        #pragma unroll
        for (int r = 0; r < 4; ++r) need = need || (tm[r] > mrow[r] + 8.f);
        if (__any(need)) {
            #pragma unroll
            for (int r = 0; r < 4; ++r) {
                float mn = fmaxf(mrow[r], tm[r]);
                float al = exp2f((mrow[r] - mn) * L2E);
                mrow[r] = mn;
                lrow[r] *= al;
                #pragma unroll
                for (int og = 0; og < 8; ++og) O[og][r] *= al;
            }
        }
        u16 p0u[4], p1u[4];
        float rs[4];
        #pragma unroll
        for (int r = 0; r < 4; ++r) {
            p0u[r] = f2h(exp2f((s0v[r] - mrow[r]) * L2E));
            p1u[r] = f2h(exp2f((s1v[r] - mrow[r]) * L2E));
            rs[r] = h2f(p0u[r]) + h2f(p1u[r]);   // denominator matches fp16 numerator mass
        }
        #pragma unroll
        for (int off = 1; off < 16; off <<= 1) {
            #pragma unroll
            for (int r = 0; r < 4; ++r) rs[r] += __shfl_xor(rs[r], off);
        }
        #pragma unroll
        for (int r = 0; r < 4; ++r) lrow[r] += rs[r];

        // P (fp16) -> per-wave LDS bounce into A-frag layout
        {
            int colm = l & 15, rowb = (l >> 4) * 4;
            #pragma unroll
            for (int mf = 0; mf < 2; ++mf) {
                int mloc = mf * 16 + colm;
                int lp = (mloc >> 3) * 16, j = mloc & 7;
                #pragma unroll
                for (int r = 0; r < 4; ++r)
                    PH[(lp + rowb + r) * 8 + j] = mf ? p1u[r] : p0u[r];
            }
        }

        // ---- O += P · VW (fp16, 8 MFMA) ----
        f16x8 pa = *(const f16x8*)(PH + l * 8);
        const f16x8* VW8 = (const f16x8*)&smem[16384 + (mc & 1) * 4096];
        __builtin_amdgcn_s_setprio(1);
        #pragma unroll
        for (int og = 0; og < 8; ++og)
            O[og] = mfma16h(pa, VW8[og * 64 + l], O[og]);
        __builtin_amdgcn_s_setprio(0);

        asm volatile("s_waitcnt vmcnt(0)" ::: "memory");
        __syncthreads();                       // barrier B: tile mc+1 staged
    }

    // epilogue: normalize + BN + ReLU, direct f32x4 store
    float inv[4];
    #pragma unroll
    for (int r = 0; r < 4; ++r) inv[r] = 1.f / lrow[r];
    int nb = ng * 16 + (l >> 4) * 4;
    #pragma unroll
    for (int og = 0; og < 8; ++og) {
        int o = og * 16 + (l & 15);
        float sc = sf[o], tb = tf[o];
        f32x4 res;
        #pragma unroll
        for (int r = 0; r < 4; ++r)
            res[r] = fmaxf(fmaf(O[og][r] * inv[r], sc, tb), 0.f);
        *(f32x4*)(out + ((size_t)b * COUT + o) * N_ + nb) = res;
    }
}

// ---------------------------------------------------------------------------
extern "C" void kernel_launch(void* const* d_in, const int* in_sizes, int n_in,
                              void* d_out, int out_size, void* d_ws, size_t ws_size,
                              hipStream_t stream)
{
    const float* x   = (const float*)d_in[0];
    const float* Wq  = (const float*)d_in[1];
    const float* Wk  = (const float*)d_in[2];
    const float* Wv  = (const float*)d_in[3];
    const float* Wf  = (const float*)d_in[4];
    const float* bnq = (const float*)d_in[5];
    const float* bnk = (const float*)d_in[6];
    const float* bnv = (const float*)d_in[7];
    const float* bnf = (const float*)d_in[8];
    float* out = (float*)d_out;

    const size_t NBUF = (size_t)B_ * N_ * C_;   // 8,388,608 u16 per buffer
    u16* qh  = (u16*)d_ws;
    u16* ql  = qh + NBUF;
    u16* kh  = ql + NBUF;
    u16* kl  = kh + NBUF;
    u16* vt  = kl + NBUF;
    u16* vwb = vt + NBUF;               // 16*2048*128 = 4,194,304 u16
    u16* wfh = vwb + 4194304;
    u16* wfl = wfh + 32768;
    u16* wAh = wfl + 32768;             // 3*16*5*64*8 = 122880 u16
    u16* wAl = wAh + 122880;
    float* sqkv = (float*)(wAl + 122880);
    float* tqkv = sqkv + 768;
    float* sf   = tqkv + 768;
    float* tf   = sf + 128;

    w_prep<<<dim3(76), dim3(256), 0, stream>>>(Wq, Wk, Wv, Wf, bnq, bnk, bnv, bnf,
                                               wAh, wAl, wfh, wfl, sqkv, tqkv, sf, tf);
    qkv_proj<<<dim3(1536), dim3(256), 0, stream>>>(x, wAh, wAl, sqkv, tqkv,
                                                   qh, ql, kh, kl, vt);
    vw_proj<<<dim3(256), dim3(256), 0, stream>>>(vt, wfh, wfl, vwb);
    attn_fwd<<<dim3(512), dim3(256), 0, stream>>>(qh, ql, kh, kl, vwb,
                                                  sf, tf, out);
}